// Round 4
// baseline (144.110 us; speedup 1.0000x reference)
//
#include <hip/hip_runtime.h>
#include <hip/hip_bf16.h>
#include <math.h>

#define D 40
#define DIN 128
#define S 2048
#define B 8
#define NROWS (B*S)   // 16384
#define DP 64         // padded depth for Q/K bf16 rows
#define DVP 64        // padded depth (rows) for transposed V

typedef __bf16 bf16x8 __attribute__((ext_vector_type(8)));
typedef float f32x4 __attribute__((ext_vector_type(4)));
typedef float f32x16 __attribute__((ext_vector_type(16)));

static __device__ __forceinline__ unsigned short f2bf(float f) {
    unsigned u = __builtin_bit_cast(unsigned, f);
    u += 0x7fff + ((u >> 16) & 1);   // RNE
    return (unsigned short)(u >> 16);
}
static __device__ __forceinline__ bf16x8 ldfrag(const unsigned short* p) {
    return __builtin_bit_cast(bf16x8, *(const uint4*)p);
}
static __device__ __forceinline__ unsigned cvtpk(float lo, float hi) {
    unsigned r;
    asm("v_cvt_pk_bf16_f32 %0, %1, %2" : "=v"(r) : "v"(lo), "v"(hi));
    return r;
}
static __device__ __forceinline__ void plswap(unsigned &a, unsigned &b) {
    // new_a[32:63] = old_b[0:31]; new_b[0:31] = old_a[32:63]
    asm("v_permlane32_swap_b32 %0, %1" : "+v"(a), "+v"(b));
}

// ---------------- Kernel 1: adapter + rmsnorm + QKV (bf16 outputs) ----------------
// 256 blocks, 64 rows/block (grid-stride): weights loaded once per block.
__global__ __launch_bounds__(256) void k1_adapter_qkv(
    const float* __restrict__ embs, const float* __restrict__ Wa,
    const float* __restrict__ ba, const float* __restrict__ ln1,
    const float* __restrict__ Wq, const float* __restrict__ Wk, const float* __restrict__ Wv,
    float* __restrict__ x, unsigned short* __restrict__ qb,
    unsigned short* __restrict__ kbq, unsigned short* __restrict__ vT)
{
    __shared__ float sWa[DIN*D];
    __shared__ float sWq[D*D], sWk[D*D], sWv[D*D];
    __shared__ float sba[D], sln[D];
    __shared__ float sE[4][DIN];
    __shared__ float sH[4][D];

    int tid = threadIdx.x;
    for (int i = tid; i < DIN*D; i += 256) sWa[i] = Wa[i];
    for (int i = tid; i < D*D; i += 256) { sWq[i]=Wq[i]; sWk[i]=Wk[i]; sWv[i]=Wv[i]; }
    if (tid < D) { sba[tid]=ba[tid]; sln[tid]=ln1[tid]; }
    __syncthreads();

    int wave = tid >> 6, lane = tid & 63;
    int base = blockIdx.x * 64;

    for (int it = 0; it < 16; ++it) {
        int row = base + it*4 + wave;
        sE[wave][lane]      = embs[row*DIN + lane];
        sE[wave][lane + 64] = embs[row*DIN + lane + 64];

        float xj = 0.f;
        if (lane < D) {
            float acc = sba[lane];
            const float4* e4 = (const float4*)&sE[wave][0];
            #pragma unroll
            for (int i = 0; i < DIN/4; ++i) {
                float4 e = e4[i];
                acc += e.x * sWa[(4*i+0)*D + lane];
                acc += e.y * sWa[(4*i+1)*D + lane];
                acc += e.z * sWa[(4*i+2)*D + lane];
                acc += e.w * sWa[(4*i+3)*D + lane];
            }
            xj = fmaxf(acc, 0.f);
            x[row*D + lane] = xj;
        }
        float ss = xj * xj;
        #pragma unroll
        for (int off = 32; off; off >>= 1) ss += __shfl_down(ss, off);
        ss = __shfl(ss, 0);
        float inv = rsqrtf(ss * (1.0f/D) + 1e-6f);
        if (lane < D) sH[wave][lane] = xj * inv * sln[lane];

        float aq = 0.f, ak = 0.f, av = 0.f;
        if (lane < D) {
            const float4* h4 = (const float4*)&sH[wave][0];
            #pragma unroll
            for (int i = 0; i < D/4; ++i) {
                float4 h = h4[i];
                aq += h.x*sWq[(4*i+0)*D+lane] + h.y*sWq[(4*i+1)*D+lane]
                    + h.z*sWq[(4*i+2)*D+lane] + h.w*sWq[(4*i+3)*D+lane];
                ak += h.x*sWk[(4*i+0)*D+lane] + h.y*sWk[(4*i+1)*D+lane]
                    + h.z*sWk[(4*i+2)*D+lane] + h.w*sWk[(4*i+3)*D+lane];
                av += h.x*sWv[(4*i+0)*D+lane] + h.y*sWv[(4*i+1)*D+lane]
                    + h.z*sWv[(4*i+2)*D+lane] + h.w*sWv[(4*i+3)*D+lane];
            }
        }
        qb [row*DP + lane] = (lane < D) ? f2bf(aq) : (unsigned short)0;
        kbq[row*DP + lane] = (lane < D) ? f2bf(ak) : (unsigned short)0;
        if (lane < D) vT[(size_t)lane*NROWS + row] = f2bf(av);
    }
}

// ---------------- Kernel 2: relative-position bias table ----------------
__global__ void k2_bias_table(const float* __restrict__ rel_bias, float* __restrict__ btab)
{
    int t = blockIdx.x * 256 + threadIdx.x;
    if (t >= 2*S - 1) return;
    int rel = t - (S - 1);          // rel = k - q
    int bucket = (rel > 0) ? 16 : 0;
    int ar = rel < 0 ? -rel : rel;
    int add;
    if (ar < 8) {
        add = ar;
    } else {
        float tt = logf((float)ar * 0.125f) / logf(16.0f) * 8.0f;
        int lg = 8 + (int)tt;
        add = lg < 15 ? lg : 15;
    }
    btab[t] = rel_bias[bucket + add];
}

// ---------------- Kernel 3: flash attention, swapped-QK^T 32x32 MFMA ----------------
// grid (S/128, B, nsplit), 256 threads = 4 waves; wave owns 32 q-rows.
// Swapped QK^T: C[k][q] (col=lane&31=q) -> softmax fully in registers;
// P -> PV A-frag via cvt_pk_bf16 + permlane32_swap (no LDS round trip).
__global__ __launch_bounds__(256) void k3_attn_mfma(
    const unsigned short* __restrict__ qb, const unsigned short* __restrict__ kb,
    const unsigned short* __restrict__ vT, const float* __restrict__ btab,
    float* __restrict__ po, float* __restrict__ pl, int klen)
{
    __shared__ float sbtw[2176 + 16];   // bias window: klen+128 <= 2176

    const int q0blk = blockIdx.x * 128;
    const int kt0   = blockIdx.z * klen;
    const int woff  = (S-1) + kt0 - q0blk - 127;

    int tid = threadIdx.x;
    for (int i = tid; i < klen + 128; i += 256) {
        int g = woff + i;
        sbtw[i] = btab[g < 0 ? 0 : (g > 4094 ? 4094 : g)];
    }
    __syncthreads();

    const int w  = tid >> 6, l = tid & 63;
    const int lr = l & 31,  hi = l >> 5;
    const int b  = blockIdx.y;
    const int q0 = q0blk + w * 32;

    // Q B-fragments (3 d-tiles of 16): B[d][q=lane&31], d-elems = dt*16 + hi*8 + j
    const unsigned short* qrow = qb + ((size_t)(b*S) + q0 + lr) * DP + hi*8;
    bf16x8 qf0 = ldfrag(qrow);
    bf16x8 qf1 = ldfrag(qrow + 16);
    bf16x8 qf2 = ldfrag(qrow + 32);

    const unsigned short* kbase = kb + ((size_t)(b*S) + lr) * DP + hi*8;
    const unsigned short* vbase = vT + (size_t)lr*NROWS + (size_t)b*S + hi*8;

    f32x16 of0 = {0,0,0,0,0,0,0,0,0,0,0,0,0,0,0,0};
    f32x16 of1 = {0,0,0,0,0,0,0,0,0,0,0,0,0,0,0,0};
    float el = 0.f;

    // bias local index: idx(r) = bb + (kt-kt0) + (r&3) + 8*(r>>2)
    const int bb = 127 - w*32 - lr + 4*hi;

    bf16x8 kfA[3], vfA[4], kfB[3], vfB[4];

    auto loadK = [&](int kt, bf16x8* kf) {
        const unsigned short* p = kbase + (size_t)kt*DP;
        kf[0] = ldfrag(p); kf[1] = ldfrag(p + 16); kf[2] = ldfrag(p + 32);
    };
    auto loadV = [&](int kt, bf16x8* vf) {
        const unsigned short* p = vbase + kt;
        vf[0] = ldfrag(p);                           // win0, d-tile0
        vf[1] = ldfrag(p + 16);                      // win1, d-tile0
        vf[2] = ldfrag(p + (size_t)32*NROWS);        // win0, d-tile1
        vf[3] = ldfrag(p + (size_t)32*NROWS + 16);   // win1, d-tile1
    };

    auto compute = [&](int ktl, const bf16x8* kf, const bf16x8* vf) {
        f32x16 c = {0,0,0,0,0,0,0,0,0,0,0,0,0,0,0,0};
        c = __builtin_amdgcn_mfma_f32_32x32x16_bf16(kf[0], qf0, c, 0,0,0);
        c = __builtin_amdgcn_mfma_f32_32x32x16_bf16(kf[1], qf1, c, 0,0,0);
        c = __builtin_amdgcn_mfma_f32_32x32x16_bf16(kf[2], qf2, c, 0,0,0);

        // bias + exp, in registers; k-row(r) = (r&3) + 8*(r>>2) + 4*hi
        float e[16];
        #pragma unroll
        for (int r = 0; r < 16; ++r) {
            float s = c[r] + sbtw[bb + ktl + (r&3) + 8*(r>>2)];
            e[r] = __expf(s);
            el += e[r];
        }
        // pack to bf16 pairs and redistribute halves -> PV A-fragments
        unsigned a0 = cvtpk(e[0],  e[1]);   // hi0: k(0,1)   hi1: k(4,5)
        unsigned a1 = cvtpk(e[2],  e[3]);   // hi0: k(2,3)   hi1: k(6,7)
        unsigned a2 = cvtpk(e[4],  e[5]);   // hi0: k(8,9)   hi1: k(12,13)
        unsigned a3 = cvtpk(e[6],  e[7]);   // hi0: k(10,11) hi1: k(14,15)
        plswap(a0, a2);  // a0 -> word0 (k base+0,1), a2 -> word2 (k base+4,5)
        plswap(a1, a3);  // a1 -> word1,              a3 -> word3
        unsigned b0 = cvtpk(e[8],  e[9]);
        unsigned b1 = cvtpk(e[10], e[11]);
        unsigned b2 = cvtpk(e[12], e[13]);
        unsigned b3 = cvtpk(e[14], e[15]);
        plswap(b0, b2);
        plswap(b1, b3);
        uint4 u0 = {a0, a1, a2, a3};
        uint4 u1 = {b0, b1, b2, b3};
        bf16x8 pa0 = __builtin_bit_cast(bf16x8, u0);   // P[q][kt + 0..15]
        bf16x8 pa1 = __builtin_bit_cast(bf16x8, u1);   // P[q][kt + 16..31]

        of0 = __builtin_amdgcn_mfma_f32_32x32x16_bf16(pa0, vf[0], of0, 0,0,0);
        of0 = __builtin_amdgcn_mfma_f32_32x32x16_bf16(pa1, vf[1], of0, 0,0,0);
        of1 = __builtin_amdgcn_mfma_f32_32x32x16_bf16(pa0, vf[2], of1, 0,0,0);
        of1 = __builtin_amdgcn_mfma_f32_32x32x16_bf16(pa1, vf[3], of1, 0,0,0);
    };

    loadK(kt0, kfA); loadV(kt0, vfA);
    for (int kt = kt0; kt < kt0 + klen; kt += 64) {
        loadK(kt+32, kfB); loadV(kt+32, vfB);
        compute(kt - kt0, kfA, vfA);
        if (kt + 64 < kt0 + klen) { loadK(kt+64, kfA); loadV(kt+64, vfA); }
        compute(kt + 32 - kt0, kfB, vfB);
    }

    el += __shfl_xor(el, 32);   // combine the two lane-halves' k-partials

    const size_t rowbase = (size_t)blockIdx.z * NROWS + b*S + q0;
    #pragma unroll
    for (int r = 0; r < 16; ++r) {
        int qr = (r&3) + 8*(r>>2) + 4*hi;
        float* pr = po + (rowbase + qr) * D;
        pr[lr] = of0[r];                       // d = 0..31
        if (lr < 8) pr[32 + lr] = of1[r];      // d = 32..39
    }
    if (hi == 0) pl[rowbase + lr] = el;
}

// ---------------- Kernel 4: split-K combine + O-proj + residual + FF + rmsnorm ----------------
__global__ __launch_bounds__(256) void k4_out_ff(
    const float* __restrict__ x, const float* __restrict__ po, const float* __restrict__ pl,
    const float* __restrict__ Wo, const float* __restrict__ ln2,
    const float* __restrict__ wi, const float* __restrict__ wo,
    const float* __restrict__ lnf, float* __restrict__ out, int nsplit)
{
    __shared__ float sWo[D*D], sWi[D*D], sWo2[D*D];
    __shared__ float sln2[D], slnf[D];
    __shared__ float sA[4][D], sB2[4][D];

    int tid = threadIdx.x;
    for (int i = tid; i < D*D; i += 256) { sWo[i]=Wo[i]; sWi[i]=wi[i]; sWo2[i]=wo[i]; }
    if (tid < D) { sln2[tid]=ln2[tid]; slnf[tid]=lnf[tid]; }
    __syncthreads();

    int wave = tid >> 6, lane = tid & 63;
    int base = blockIdx.x * 64;

    for (int it = 0; it < 16; ++it) {
        int row = base + it*4 + wave;

        float lsum = 0.f;
        for (int s = 0; s < nsplit; ++s) lsum += pl[(size_t)s*NROWS + row];
        float linv = 1.0f / lsum;
        if (lane < D) {
            float acc = 0.f;
            for (int s = 0; s < nsplit; ++s) acc += po[((size_t)s*NROWS + row)*D + lane];
            sA[wave][lane] = acc * linv;
        }

        float x2 = 0.f;
        if (lane < D) {
            float acc = 0.f;
            const float4* a4 = (const float4*)&sA[wave][0];
            #pragma unroll
            for (int i = 0; i < D/4; ++i) {
                float4 a = a4[i];
                acc += a.x*sWo[(4*i+0)*D+lane] + a.y*sWo[(4*i+1)*D+lane]
                     + a.z*sWo[(4*i+2)*D+lane] + a.w*sWo[(4*i+3)*D+lane];
            }
            x2 = x[row*D + lane] + acc;
        }
        float ss = x2 * x2;
        #pragma unroll
        for (int off = 32; off; off >>= 1) ss += __shfl_down(ss, off);
        ss = __shfl(ss, 0);
        float inv = rsqrtf(ss * (1.0f/D) + 1e-6f);
        if (lane < D) sB2[wave][lane] = x2 * inv * sln2[lane];

        float f1 = 0.f;
        if (lane < D) {
            float acc = 0.f;
            const float4* b4 = (const float4*)&sB2[wave][0];
            #pragma unroll
            for (int i = 0; i < D/4; ++i) {
                float4 h = b4[i];
                acc += h.x*sWi[(4*i+0)*D+lane] + h.y*sWi[(4*i+1)*D+lane]
                     + h.z*sWi[(4*i+2)*D+lane] + h.w*sWi[(4*i+3)*D+lane];
            }
            f1 = fmaxf(acc, 0.f);
            sA[wave][lane] = f1;
        }

        float x3 = 0.f;
        if (lane < D) {
            float acc = 0.f;
            const float4* a4 = (const float4*)&sA[wave][0];
            #pragma unroll
            for (int i = 0; i < D/4; ++i) {
                float4 h = a4[i];
                acc += h.x*sWo2[(4*i+0)*D+lane] + h.y*sWo2[(4*i+1)*D+lane]
                     + h.z*sWo2[(4*i+2)*D+lane] + h.w*sWo2[(4*i+3)*D+lane];
            }
            x3 = x2 + acc;
        }
        float ss2 = x3 * x3;
        #pragma unroll
        for (int off = 32; off; off >>= 1) ss2 += __shfl_down(ss2, off);
        ss2 = __shfl(ss2, 0);
        float inv2 = rsqrtf(ss2 * (1.0f/D) + 1e-6f);
        if (lane < D) out[row*D + lane] = x3 * inv2 * slnf[lane];
    }
}

extern "C" void kernel_launch(void* const* d_in, const int* in_sizes, int n_in,
                              void* d_out, int out_size, void* d_ws, size_t ws_size,
                              hipStream_t stream) {
    const float* embs = (const float*)d_in[0];
    const float* Wa   = (const float*)d_in[1];
    const float* ba   = (const float*)d_in[2];
    const float* ln1  = (const float*)d_in[3];
    const float* Wq   = (const float*)d_in[4];
    const float* Wk   = (const float*)d_in[5];
    const float* Wv   = (const float*)d_in[6];
    const float* Wo   = (const float*)d_in[7];
    const float* ln2  = (const float*)d_in[8];
    const float* wi   = (const float*)d_in[9];
    const float* wo   = (const float*)d_in[10];
    const float* lnf  = (const float*)d_in[11];
    const float* rb   = (const float*)d_in[12];

    char* wsb = (char*)d_ws;
    float*          x    = (float*)(wsb);                       // 2,621,440 B
    unsigned short* qb   = (unsigned short*)(wsb + 2621440);    // 2,097,152 B
    unsigned short* kbq  = (unsigned short*)(wsb + 4718592);    // 2,097,152 B
    unsigned short* vT   = (unsigned short*)(wsb + 6815744);    // 64*NROWS*2 = 2,097,152 B
    // po/pl/btab after vT, sized by nsplit

    int nsplit = 4;
    while (nsplit > 1 &&
           (size_t)8912896 + (size_t)nsplit*(2621440 + 65536) + 16384 > ws_size)
        nsplit >>= 1;
    float* po   = (float*)(wsb + 8912896);
    float* pl   = (float*)(wsb + 8912896 + (size_t)nsplit*2621440);
    float* btab = (float*)(wsb + 8912896 + (size_t)nsplit*(2621440 + 65536));
    int klen = S / nsplit;

    // zero V-pad rows d=40..63
    (void)hipMemsetAsync(vT + (size_t)D*NROWS, 0, (size_t)(DVP - D)*NROWS*2, stream);

    k1_adapter_qkv<<<256, 256, 0, stream>>>(embs, Wa, ba, ln1, Wq, Wk, Wv, x, qb, kbq, vT);
    k2_bias_table<<<16, 256, 0, stream>>>(rb, btab);
    k3_attn_mfma<<<dim3(S/128, B, nsplit), 256, 0, stream>>>(qb, kbq, vT, btab, po, pl, klen);
    k4_out_ff<<<256, 256, 0, stream>>>(x, po, pl, Wo, ln2, wi, wo, lnf, (float*)d_out, nsplit);
}

// Round 5
// 117.799 us; speedup vs baseline: 1.2234x; 1.2234x over previous
//
#include <hip/hip_runtime.h>
#include <hip/hip_bf16.h>
#include <math.h>

#define D 40
#define DIN 128
#define S 2048
#define B 8
#define NROWS (B*S)   // 16384
#define DP 64         // padded depth for Q/K bf16 rows
#define DVP 64        // padded depth (rows) for transposed V

typedef __bf16 bf16x8 __attribute__((ext_vector_type(8)));
typedef float f32x4 __attribute__((ext_vector_type(4)));
typedef float f32x16 __attribute__((ext_vector_type(16)));

static __device__ __forceinline__ unsigned short f2bf(float f) {
    unsigned u = __builtin_bit_cast(unsigned, f);
    u += 0x7fff + ((u >> 16) & 1);   // RNE
    return (unsigned short)(u >> 16);
}
static __device__ __forceinline__ bf16x8 ldfrag(const unsigned short* p) {
    return __builtin_bit_cast(bf16x8, *(const uint4*)p);
}
static __device__ __forceinline__ unsigned cvtpk(float lo, float hi) {
    unsigned r;
    asm("v_cvt_pk_bf16_f32 %0, %1, %2" : "=v"(r) : "v"(lo), "v"(hi));
    return r;
}
static __device__ __forceinline__ void plswap(unsigned &a, unsigned &b) {
    asm("v_permlane32_swap_b32 %0, %1" : "+v"(a), "+v"(b));
}

// ---------------- Kernel 1: adapter + rmsnorm + QKV (bf16 outputs) ----------------
// 1024 blocks, 16 rows/block; weights staged in LDS; wave-private row slices,
// no in-loop __syncthreads; split accumulators to shorten dependent FMA chains.
__global__ __launch_bounds__(256) void k1_adapter_qkv(
    const float* __restrict__ embs, const float* __restrict__ Wa,
    const float* __restrict__ ba, const float* __restrict__ ln1,
    const float* __restrict__ Wq, const float* __restrict__ Wk, const float* __restrict__ Wv,
    float* __restrict__ x, unsigned short* __restrict__ qb,
    unsigned short* __restrict__ kbq, unsigned short* __restrict__ vT)
{
    __shared__ float sWa[DIN*D];
    __shared__ float sWq[D*D], sWk[D*D], sWv[D*D];
    __shared__ float sba[D], sln[D];
    __shared__ float sE[4][DIN];
    __shared__ float sH[4][D];

    int tid = threadIdx.x;
    for (int i = tid; i < DIN*D; i += 256) sWa[i] = Wa[i];
    for (int i = tid; i < D*D; i += 256) { sWq[i]=Wq[i]; sWk[i]=Wk[i]; sWv[i]=Wv[i]; }
    if (tid < D) { sba[tid]=ba[tid]; sln[tid]=ln1[tid]; }
    __syncthreads();

    int wave = tid >> 6, lane = tid & 63;
    int base = blockIdx.x * 16;

    for (int it = 0; it < 4; ++it) {
        int row = base + it*4 + wave;
        sE[wave][lane]      = embs[row*DIN + lane];
        sE[wave][lane + 64] = embs[row*DIN + lane + 64];

        float xj = 0.f;
        if (lane < D) {
            float a0 = sba[lane], a1 = 0.f, a2 = 0.f, a3 = 0.f;
            const float4* e4 = (const float4*)&sE[wave][0];
            #pragma unroll
            for (int i = 0; i < DIN/4; ++i) {
                float4 e = e4[i];
                a0 += e.x * sWa[(4*i+0)*D + lane];
                a1 += e.y * sWa[(4*i+1)*D + lane];
                a2 += e.z * sWa[(4*i+2)*D + lane];
                a3 += e.w * sWa[(4*i+3)*D + lane];
            }
            xj = fmaxf((a0 + a1) + (a2 + a3), 0.f);
            x[row*D + lane] = xj;
        }
        float ss = xj * xj;
        #pragma unroll
        for (int off = 32; off; off >>= 1) ss += __shfl_down(ss, off);
        ss = __shfl(ss, 0);
        float inv = rsqrtf(ss * (1.0f/D) + 1e-6f);
        if (lane < D) sH[wave][lane] = xj * inv * sln[lane];

        float aq = 0.f, ak = 0.f, av = 0.f;
        if (lane < D) {
            float q0=0.f,q1=0.f,k0=0.f,k1=0.f,v0=0.f,v1=0.f;
            const float4* h4 = (const float4*)&sH[wave][0];
            #pragma unroll
            for (int i = 0; i < D/4; ++i) {
                float4 h = h4[i];
                q0 += h.x*sWq[(4*i+0)*D+lane] + h.y*sWq[(4*i+1)*D+lane];
                q1 += h.z*sWq[(4*i+2)*D+lane] + h.w*sWq[(4*i+3)*D+lane];
                k0 += h.x*sWk[(4*i+0)*D+lane] + h.y*sWk[(4*i+1)*D+lane];
                k1 += h.z*sWk[(4*i+2)*D+lane] + h.w*sWk[(4*i+3)*D+lane];
                v0 += h.x*sWv[(4*i+0)*D+lane] + h.y*sWv[(4*i+1)*D+lane];
                v1 += h.z*sWv[(4*i+2)*D+lane] + h.w*sWv[(4*i+3)*D+lane];
            }
            aq = q0 + q1; ak = k0 + k1; av = v0 + v1;
        }
        qb [row*DP + lane] = (lane < D) ? f2bf(aq) : (unsigned short)0;
        kbq[row*DP + lane] = (lane < D) ? f2bf(ak) : (unsigned short)0;
        if (lane < D) vT[(size_t)lane*NROWS + row] = f2bf(av);
    }
}

// ---------------- Kernel 2: relative-position bias table ----------------
__global__ void k2_bias_table(const float* __restrict__ rel_bias, float* __restrict__ btab)
{
    int t = blockIdx.x * 256 + threadIdx.x;
    if (t >= 2*S - 1) return;
    int rel = t - (S - 1);          // rel = k - q
    int bucket = (rel > 0) ? 16 : 0;
    int ar = rel < 0 ? -rel : rel;
    int add;
    if (ar < 8) {
        add = ar;
    } else {
        float tt = logf((float)ar * 0.125f) / logf(16.0f) * 8.0f;
        int lg = 8 + (int)tt;
        add = lg < 15 ? lg : 15;
    }
    btab[t] = rel_bias[bucket + add];
}

// ---------------- Kernel 3: flash attention, swapped-QK^T 32x32 MFMA ----------------
// (unchanged from round 4 — in-register softmax via cvt_pk + permlane32_swap)
__global__ __launch_bounds__(256) void k3_attn_mfma(
    const unsigned short* __restrict__ qb, const unsigned short* __restrict__ kb,
    const unsigned short* __restrict__ vT, const float* __restrict__ btab,
    float* __restrict__ po, float* __restrict__ pl, int klen)
{
    __shared__ float sbtw[2176 + 16];

    const int q0blk = blockIdx.x * 128;
    const int kt0   = blockIdx.z * klen;
    const int woff  = (S-1) + kt0 - q0blk - 127;

    int tid = threadIdx.x;
    for (int i = tid; i < klen + 128; i += 256) {
        int g = woff + i;
        sbtw[i] = btab[g < 0 ? 0 : (g > 4094 ? 4094 : g)];
    }
    __syncthreads();

    const int w  = tid >> 6, l = tid & 63;
    const int lr = l & 31,  hi = l >> 5;
    const int b  = blockIdx.y;
    const int q0 = q0blk + w * 32;

    const unsigned short* qrow = qb + ((size_t)(b*S) + q0 + lr) * DP + hi*8;
    bf16x8 qf0 = ldfrag(qrow);
    bf16x8 qf1 = ldfrag(qrow + 16);
    bf16x8 qf2 = ldfrag(qrow + 32);

    const unsigned short* kbase = kb + ((size_t)(b*S) + lr) * DP + hi*8;
    const unsigned short* vbase = vT + (size_t)lr*NROWS + (size_t)b*S + hi*8;

    f32x16 of0 = {0,0,0,0,0,0,0,0,0,0,0,0,0,0,0,0};
    f32x16 of1 = {0,0,0,0,0,0,0,0,0,0,0,0,0,0,0,0};
    float el = 0.f;

    const int bb = 127 - w*32 - lr + 4*hi;

    bf16x8 kfA[3], vfA[4], kfB[3], vfB[4];

    auto loadK = [&](int kt, bf16x8* kf) {
        const unsigned short* p = kbase + (size_t)kt*DP;
        kf[0] = ldfrag(p); kf[1] = ldfrag(p + 16); kf[2] = ldfrag(p + 32);
    };
    auto loadV = [&](int kt, bf16x8* vf) {
        const unsigned short* p = vbase + kt;
        vf[0] = ldfrag(p);
        vf[1] = ldfrag(p + 16);
        vf[2] = ldfrag(p + (size_t)32*NROWS);
        vf[3] = ldfrag(p + (size_t)32*NROWS + 16);
    };

    auto compute = [&](int ktl, const bf16x8* kf, const bf16x8* vf) {
        f32x16 c = {0,0,0,0,0,0,0,0,0,0,0,0,0,0,0,0};
        c = __builtin_amdgcn_mfma_f32_32x32x16_bf16(kf[0], qf0, c, 0,0,0);
        c = __builtin_amdgcn_mfma_f32_32x32x16_bf16(kf[1], qf1, c, 0,0,0);
        c = __builtin_amdgcn_mfma_f32_32x32x16_bf16(kf[2], qf2, c, 0,0,0);

        float e[16];
        #pragma unroll
        for (int r = 0; r < 16; ++r) {
            float s = c[r] + sbtw[bb + ktl + (r&3) + 8*(r>>2)];
            e[r] = __expf(s);
            el += e[r];
        }
        unsigned a0 = cvtpk(e[0],  e[1]);
        unsigned a1 = cvtpk(e[2],  e[3]);
        unsigned a2 = cvtpk(e[4],  e[5]);
        unsigned a3 = cvtpk(e[6],  e[7]);
        plswap(a0, a2);
        plswap(a1, a3);
        unsigned b0 = cvtpk(e[8],  e[9]);
        unsigned b1 = cvtpk(e[10], e[11]);
        unsigned b2 = cvtpk(e[12], e[13]);
        unsigned b3 = cvtpk(e[14], e[15]);
        plswap(b0, b2);
        plswap(b1, b3);
        uint4 u0 = {a0, a1, a2, a3};
        uint4 u1 = {b0, b1, b2, b3};
        bf16x8 pa0 = __builtin_bit_cast(bf16x8, u0);
        bf16x8 pa1 = __builtin_bit_cast(bf16x8, u1);

        of0 = __builtin_amdgcn_mfma_f32_32x32x16_bf16(pa0, vf[0], of0, 0,0,0);
        of0 = __builtin_amdgcn_mfma_f32_32x32x16_bf16(pa1, vf[1], of0, 0,0,0);
        of1 = __builtin_amdgcn_mfma_f32_32x32x16_bf16(pa0, vf[2], of1, 0,0,0);
        of1 = __builtin_amdgcn_mfma_f32_32x32x16_bf16(pa1, vf[3], of1, 0,0,0);
    };

    loadK(kt0, kfA); loadV(kt0, vfA);
    for (int kt = kt0; kt < kt0 + klen; kt += 64) {
        loadK(kt+32, kfB); loadV(kt+32, vfB);
        compute(kt - kt0, kfA, vfA);
        if (kt + 64 < kt0 + klen) { loadK(kt+64, kfA); loadV(kt+64, vfA); }
        compute(kt + 32 - kt0, kfB, vfB);
    }

    el += __shfl_xor(el, 32);

    const size_t rowbase = (size_t)blockIdx.z * NROWS + b*S + q0;
    #pragma unroll
    for (int r = 0; r < 16; ++r) {
        int qr = (r&3) + 8*(r>>2) + 4*hi;
        float* pr = po + (rowbase + qr) * D;
        pr[lr] = of0[r];
        if (lr < 8) pr[32 + lr] = of1[r];
    }
    if (hi == 0) pl[rowbase + lr] = el;
}

// ---------------- Kernel 4: split-K combine + O-proj + residual + FF + rmsnorm ----------------
// 2048 blocks, 8 rows/block; weights read directly from global (19.2 KB, fits
// L1); LDS only for tiny row-broadcast slices -> occupancy wave-capped.
__global__ __launch_bounds__(256) void k4_out_ff(
    const float* __restrict__ x, const float* __restrict__ po, const float* __restrict__ pl,
    const float* __restrict__ Wo, const float* __restrict__ ln2,
    const float* __restrict__ wi, const float* __restrict__ wo,
    const float* __restrict__ lnf, float* __restrict__ out, int nsplit)
{
    __shared__ float sA[4][D], sB2[4][D];

    int tid = threadIdx.x;
    int wave = tid >> 6, lane = tid & 63;
    int base = blockIdx.x * 8;

    for (int it = 0; it < 2; ++it) {
        int row = base + it*4 + wave;

        float lsum = 0.f;
        for (int s = 0; s < nsplit; ++s) lsum += pl[(size_t)s*NROWS + row];
        float linv = 1.0f / lsum;
        if (lane < D) {
            float acc = 0.f;
            for (int s = 0; s < nsplit; ++s) acc += po[((size_t)s*NROWS + row)*D + lane];
            sA[wave][lane] = acc * linv;
        }

        float x2 = 0.f;
        if (lane < D) {
            float a0=0.f,a1=0.f,a2=0.f,a3=0.f;
            const float4* a4 = (const float4*)&sA[wave][0];
            #pragma unroll
            for (int i = 0; i < D/4; ++i) {
                float4 a = a4[i];
                a0 += a.x*Wo[(4*i+0)*D+lane];
                a1 += a.y*Wo[(4*i+1)*D+lane];
                a2 += a.z*Wo[(4*i+2)*D+lane];
                a3 += a.w*Wo[(4*i+3)*D+lane];
            }
            x2 = x[row*D + lane] + (a0+a1) + (a2+a3);
        }
        float ss = x2 * x2;
        #pragma unroll
        for (int off = 32; off; off >>= 1) ss += __shfl_down(ss, off);
        ss = __shfl(ss, 0);
        float inv = rsqrtf(ss * (1.0f/D) + 1e-6f);
        if (lane < D) sB2[wave][lane] = x2 * inv * ln2[lane];

        float f1 = 0.f;
        if (lane < D) {
            float a0=0.f,a1=0.f,a2=0.f,a3=0.f;
            const float4* b4 = (const float4*)&sB2[wave][0];
            #pragma unroll
            for (int i = 0; i < D/4; ++i) {
                float4 h = b4[i];
                a0 += h.x*wi[(4*i+0)*D+lane];
                a1 += h.y*wi[(4*i+1)*D+lane];
                a2 += h.z*wi[(4*i+2)*D+lane];
                a3 += h.w*wi[(4*i+3)*D+lane];
            }
            f1 = fmaxf((a0+a1) + (a2+a3), 0.f);
            sA[wave][lane] = f1;
        }

        float x3 = 0.f;
        if (lane < D) {
            float a0=0.f,a1=0.f,a2=0.f,a3=0.f;
            const float4* a4 = (const float4*)&sA[wave][0];
            #pragma unroll
            for (int i = 0; i < D/4; ++i) {
                float4 h = a4[i];
                a0 += h.x*wo[(4*i+0)*D+lane];
                a1 += h.y*wo[(4*i+1)*D+lane];
                a2 += h.z*wo[(4*i+2)*D+lane];
                a3 += h.w*wo[(4*i+3)*D+lane];
            }
            x3 = x2 + (a0+a1) + (a2+a3);
        }
        float ss2 = x3 * x3;
        #pragma unroll
        for (int off = 32; off; off >>= 1) ss2 += __shfl_down(ss2, off);
        ss2 = __shfl(ss2, 0);
        float inv2 = rsqrtf(ss2 * (1.0f/D) + 1e-6f);
        if (lane < D) out[row*D + lane] = x3 * inv2 * lnf[lane];
    }
}

extern "C" void kernel_launch(void* const* d_in, const int* in_sizes, int n_in,
                              void* d_out, int out_size, void* d_ws, size_t ws_size,
                              hipStream_t stream) {
    const float* embs = (const float*)d_in[0];
    const float* Wa   = (const float*)d_in[1];
    const float* ba   = (const float*)d_in[2];
    const float* ln1  = (const float*)d_in[3];
    const float* Wq   = (const float*)d_in[4];
    const float* Wk   = (const float*)d_in[5];
    const float* Wv   = (const float*)d_in[6];
    const float* Wo   = (const float*)d_in[7];
    const float* ln2  = (const float*)d_in[8];
    const float* wi   = (const float*)d_in[9];
    const float* wo   = (const float*)d_in[10];
    const float* lnf  = (const float*)d_in[11];
    const float* rb   = (const float*)d_in[12];

    char* wsb = (char*)d_ws;
    float*          x    = (float*)(wsb);                       // 2,621,440 B
    unsigned short* qb   = (unsigned short*)(wsb + 2621440);    // 2,097,152 B
    unsigned short* kbq  = (unsigned short*)(wsb + 4718592);    // 2,097,152 B
    unsigned short* vT   = (unsigned short*)(wsb + 6815744);    // 2,097,152 B

    int nsplit = 4;
    while (nsplit > 1 &&
           (size_t)8912896 + (size_t)nsplit*(2621440 + 65536) + 16384 > ws_size)
        nsplit >>= 1;
    float* po   = (float*)(wsb + 8912896);
    float* pl   = (float*)(wsb + 8912896 + (size_t)nsplit*2621440);
    float* btab = (float*)(wsb + 8912896 + (size_t)nsplit*(2621440 + 65536));
    int klen = S / nsplit;

    (void)hipMemsetAsync(vT + (size_t)D*NROWS, 0, (size_t)(DVP - D)*NROWS*2, stream);

    k1_adapter_qkv<<<NROWS/16, 256, 0, stream>>>(embs, Wa, ba, ln1, Wq, Wk, Wv, x, qb, kbq, vT);
    k2_bias_table<<<16, 256, 0, stream>>>(rb, btab);
    k3_attn_mfma<<<dim3(S/128, B, nsplit), 256, 0, stream>>>(qb, kbq, vT, btab, po, pl, klen);
    k4_out_ff<<<NROWS/8, 256, 0, stream>>>(x, po, pl, Wo, ln2, wi, wo, lnf, (float*)d_out, nsplit);
}

// Round 6
// 92.329 us; speedup vs baseline: 1.5608x; 1.2759x over previous
//
#include <hip/hip_runtime.h>
#include <hip/hip_bf16.h>
#include <math.h>

#define D 40
#define DIN 128
#define S 2048
#define B 8
#define NROWS (B*S)   // 16384
#define DP 64         // padded depth for Q/K bf16 rows
#define DVP 64        // padded depth (rows) for transposed V
#define XSTR 48       // xb row stride (ushorts)

typedef __bf16 bf16x8 __attribute__((ext_vector_type(8)));
typedef float f32x4 __attribute__((ext_vector_type(4)));
typedef float f32x16 __attribute__((ext_vector_type(16)));

static __device__ __forceinline__ unsigned short f2bf(float f) {
    unsigned u = __builtin_bit_cast(unsigned, f);
    u += 0x7fff + ((u >> 16) & 1);   // RNE
    return (unsigned short)(u >> 16);
}
static __device__ __forceinline__ float bf2f(unsigned short h) {
    return __builtin_bit_cast(float, (unsigned)h << 16);
}
static __device__ __forceinline__ bf16x8 ldfrag(const unsigned short* p) {
    return __builtin_bit_cast(bf16x8, *(const uint4*)p);
}
static __device__ __forceinline__ unsigned cvtpk(float lo, float hi) {
    unsigned r;
    asm("v_cvt_pk_bf16_f32 %0, %1, %2" : "=v"(r) : "v"(lo), "v"(hi));
    return r;
}
static __device__ __forceinline__ void plswap(unsigned &a, unsigned &b) {
    asm("v_permlane32_swap_b32 %0, %1" : "+v"(a), "+v"(b));
}

// ---------------- Kernel 0: weight prep (bf16 transposes, ba/ln1 folded) ----------------
// waT[col][k]: k<128 -> Wa[k][col]; k==128 -> ba[col]; else 0. col>=40 -> 0.
// w{q,k,v}T[col][d] = W[d][col] * ln1[d]  (rmsnorm scale folded into d-dim).
__global__ __launch_bounds__(256) void k0_prep(
    const float* __restrict__ Wa, const float* __restrict__ ba, const float* __restrict__ ln1,
    const float* __restrict__ Wq, const float* __restrict__ Wk, const float* __restrict__ Wv,
    unsigned short* __restrict__ waT, unsigned short* __restrict__ wqT,
    unsigned short* __restrict__ wkT, unsigned short* __restrict__ wvT)
{
    int i = blockIdx.x * 256 + threadIdx.x;
    if (i < 64*144) {
        int col = i / 144, k = i - col*144;
        float v = 0.f;
        if (col < D) {
            if (k < DIN) v = Wa[k*D + col];
            else if (k == DIN) v = ba[col];
        }
        waT[i] = f2bf(v);
    }
    if (i < 64*48) {
        int col = i / 48, d = i - col*48;
        float s = (col < D && d < D) ? ln1[d] : 0.f;
        wqT[i] = f2bf((col < D && d < D) ? Wq[d*D + col] * s : 0.f);
        wkT[i] = f2bf((col < D && d < D) ? Wk[d*D + col] * s : 0.f);
        wvT[i] = f2bf((col < D && d < D) ? Wv[d*D + col] * s : 0.f);
    }
}

// ---------------- Kernel 1: adapter + rmsnorm + QKV, all-MFMA ----------------
// 512 blocks x 64 threads; wave owns 32 rows. C[col][row] layout throughout
// (col = reg-slice, row = lane&31); repack to row-major frags via
// cvt_pk_bf16 + permlane32_swap (validated in k3).
__global__ __launch_bounds__(64) void k1_adapter_qkv(
    const float* __restrict__ embs,
    const unsigned short* __restrict__ waT, const unsigned short* __restrict__ wqT,
    const unsigned short* __restrict__ wkT, const unsigned short* __restrict__ wvT,
    unsigned short* __restrict__ xb, unsigned short* __restrict__ qb,
    unsigned short* __restrict__ kbq, unsigned short* __restrict__ vT)
{
    const int l  = threadIdx.x;
    const int lr = l & 31, hi = l >> 5;
    const int row = blockIdx.x * 32 + lr;     // global row for B-operands / stores

    // E B-fragments: element j = E[row][kk*16 + hi*8 + j], bf16
    const float* erow = embs + (size_t)row * DIN;
    bf16x8 eb[9];
    #pragma unroll
    for (int kk = 0; kk < 8; ++kk) {
        float4 f0 = *(const float4*)(erow + kk*16 + hi*8);
        float4 f1 = *(const float4*)(erow + kk*16 + hi*8 + 4);
        uint4 u = { cvtpk(f0.x, f0.y), cvtpk(f0.z, f0.w),
                    cvtpk(f1.x, f1.y), cvtpk(f1.z, f1.w) };
        eb[kk] = __builtin_bit_cast(bf16x8, u);
    }
    {   // k=128 constant-1 element (bias row); k=129..143 zero
        uint4 u = { hi == 0 ? 0x3f80u : 0u, 0u, 0u, 0u };
        eb[8] = __builtin_bit_cast(bf16x8, u);
    }

    // adapter: x[col][row], col-tiles 0..31 / 32..63
    f32x16 x0 = {0,0,0,0,0,0,0,0,0,0,0,0,0,0,0,0};
    f32x16 x1 = {0,0,0,0,0,0,0,0,0,0,0,0,0,0,0,0};
    #pragma unroll
    for (int kk = 0; kk < 9; ++kk) {
        bf16x8 a0 = ldfrag(waT + lr*144      + kk*16 + hi*8);
        bf16x8 a1 = ldfrag(waT + (32+lr)*144 + kk*16 + hi*8);
        x0 = __builtin_amdgcn_mfma_f32_32x32x16_bf16(a0, eb[kk], x0, 0,0,0);
        x1 = __builtin_amdgcn_mfma_f32_32x32x16_bf16(a1, eb[kk], x1, 0,0,0);
    }

    // relu + row sum-of-squares (pad cols are exactly 0)
    float ss = 0.f;
    #pragma unroll
    for (int r = 0; r < 16; ++r) {
        x0[r] = fmaxf(x0[r], 0.f);
        x1[r] = fmaxf(x1[r], 0.f);
        ss += x0[r]*x0[r] + x1[r]*x1[r];
    }
    ss += __shfl_xor(ss, 32);
    const float inv = rsqrtf(ss * (1.0f/D) + 1e-6f);

    // C-layout -> row-major bf16 frags: u0=cols hi*8+0..7 base0, u1=base16, u2=base32
    auto repack = [&](const f32x16& t0, const f32x16& t1, uint4& u0, uint4& u1, uint4& u2) {
        unsigned a0=cvtpk(t0[0],t0[1]),  a1=cvtpk(t0[2],t0[3]),
                 a2=cvtpk(t0[4],t0[5]),  a3=cvtpk(t0[6],t0[7]);
        plswap(a0,a2); plswap(a1,a3);
        unsigned b0=cvtpk(t0[8],t0[9]),  b1=cvtpk(t0[10],t0[11]),
                 b2=cvtpk(t0[12],t0[13]),b3=cvtpk(t0[14],t0[15]);
        plswap(b0,b2); plswap(b1,b3);
        unsigned c0=cvtpk(t1[0],t1[1]),  c1=cvtpk(t1[2],t1[3]),
                 c2=cvtpk(t1[4],t1[5]),  c3=cvtpk(t1[6],t1[7]);
        plswap(c0,c2); plswap(c1,c3);
        u0 = (uint4){a0,a1,a2,a3}; u1 = (uint4){b0,b1,b2,b3}; u2 = (uint4){c0,c1,c2,c3};
    };

    // residual x (pre-norm) -> xb bf16, stride 48
    {
        uint4 u0,u1,u2; repack(x0, x1, u0, u1, u2);
        unsigned short* p = xb + (size_t)row*XSTR;
        *(uint4*)(p + hi*8)      = u0;
        *(uint4*)(p + 16 + hi*8) = u1;
        *(uint4*)(p + 32 + hi*8) = u2;   // cols 40..47 are zeros, fits stride 48
    }

    // H = x * inv (ln1 folded into W'), as B-fragments for QKV
    #pragma unroll
    for (int r = 0; r < 16; ++r) { x0[r] *= inv; x1[r] *= inv; }
    uint4 h0,h1,h2; repack(x0, x1, h0, h1, h2);
    bf16x8 hb[3] = { __builtin_bit_cast(bf16x8, h0),
                     __builtin_bit_cast(bf16x8, h1),
                     __builtin_bit_cast(bf16x8, h2) };

    // QKV: C2[col][row] = sum_d W'T[col][d] * H[d][row]
    f32x16 qa0={0,0,0,0,0,0,0,0,0,0,0,0,0,0,0,0}, qa1={0,0,0,0,0,0,0,0,0,0,0,0,0,0,0,0};
    f32x16 ka0={0,0,0,0,0,0,0,0,0,0,0,0,0,0,0,0}, ka1={0,0,0,0,0,0,0,0,0,0,0,0,0,0,0,0};
    f32x16 va0={0,0,0,0,0,0,0,0,0,0,0,0,0,0,0,0}, va1={0,0,0,0,0,0,0,0,0,0,0,0,0,0,0,0};
    #pragma unroll
    for (int t = 0; t < 3; ++t) {
        bf16x8 h = hb[t];
        qa0 = __builtin_amdgcn_mfma_f32_32x32x16_bf16(ldfrag(wqT + lr*48      + t*16 + hi*8), h, qa0, 0,0,0);
        qa1 = __builtin_amdgcn_mfma_f32_32x32x16_bf16(ldfrag(wqT + (32+lr)*48 + t*16 + hi*8), h, qa1, 0,0,0);
        ka0 = __builtin_amdgcn_mfma_f32_32x32x16_bf16(ldfrag(wkT + lr*48      + t*16 + hi*8), h, ka0, 0,0,0);
        ka1 = __builtin_amdgcn_mfma_f32_32x32x16_bf16(ldfrag(wkT + (32+lr)*48 + t*16 + hi*8), h, ka1, 0,0,0);
        va0 = __builtin_amdgcn_mfma_f32_32x32x16_bf16(ldfrag(wvT + lr*48      + t*16 + hi*8), h, va0, 0,0,0);
        va1 = __builtin_amdgcn_mfma_f32_32x32x16_bf16(ldfrag(wvT + (32+lr)*48 + t*16 + hi*8), h, va1, 0,0,0);
    }

    {   // Q -> qb[row][0..47] (cols 40..47 zero; 48..63 unused by k3)
        uint4 u0,u1,u2; repack(qa0, qa1, u0, u1, u2);
        unsigned short* p = qb + (size_t)row*DP;
        *(uint4*)(p + hi*8) = u0; *(uint4*)(p + 16 + hi*8) = u1; *(uint4*)(p + 32 + hi*8) = u2;
    }
    {   // K -> kbq
        uint4 u0,u1,u2; repack(ka0, ka1, u0, u1, u2);
        unsigned short* p = kbq + (size_t)row*DP;
        *(uint4*)(p + hi*8) = u0; *(uint4*)(p + 16 + hi*8) = u1; *(uint4*)(p + 32 + hi*8) = u2;
    }
    // V -> vT[d][row] (transposed, scattered 2B)
    #pragma unroll
    for (int r = 0; r < 16; ++r) {
        int col = (r&3) + 8*(r>>2) + 4*hi;
        vT[(size_t)col*NROWS + row] = f2bf(va0[r]);
        if (r < 4) vT[(size_t)(32 + (r&3) + 4*hi)*NROWS + row] = f2bf(va1[r]);
    }
}

// ---------------- Kernel 2: relative-position bias table ----------------
__global__ void k2_bias_table(const float* __restrict__ rel_bias, float* __restrict__ btab)
{
    int t = blockIdx.x * 256 + threadIdx.x;
    if (t >= 2*S - 1) return;
    int rel = t - (S - 1);          // rel = k - q
    int bucket = (rel > 0) ? 16 : 0;
    int ar = rel < 0 ? -rel : rel;
    int add;
    if (ar < 8) {
        add = ar;
    } else {
        float tt = logf((float)ar * 0.125f) / logf(16.0f) * 8.0f;
        int lg = 8 + (int)tt;
        add = lg < 15 ? lg : 15;
    }
    btab[t] = rel_bias[bucket + add];
}

// ---------------- Kernel 3: flash attention, swapped-QK^T 32x32 MFMA ----------------
// (unchanged — in-register softmax via cvt_pk + permlane32_swap)
__global__ __launch_bounds__(256) void k3_attn_mfma(
    const unsigned short* __restrict__ qb, const unsigned short* __restrict__ kb,
    const unsigned short* __restrict__ vT, const float* __restrict__ btab,
    float* __restrict__ po, float* __restrict__ pl, int klen)
{
    __shared__ float sbtw[2176 + 16];

    const int q0blk = blockIdx.x * 128;
    const int kt0   = blockIdx.z * klen;
    const int woff  = (S-1) + kt0 - q0blk - 127;

    int tid = threadIdx.x;
    for (int i = tid; i < klen + 128; i += 256) {
        int g = woff + i;
        sbtw[i] = btab[g < 0 ? 0 : (g > 4094 ? 4094 : g)];
    }
    __syncthreads();

    const int w  = tid >> 6, l = tid & 63;
    const int lr = l & 31,  hi = l >> 5;
    const int b  = blockIdx.y;
    const int q0 = q0blk + w * 32;

    const unsigned short* qrow = qb + ((size_t)(b*S) + q0 + lr) * DP + hi*8;
    bf16x8 qf0 = ldfrag(qrow);
    bf16x8 qf1 = ldfrag(qrow + 16);
    bf16x8 qf2 = ldfrag(qrow + 32);

    const unsigned short* kbase = kb + ((size_t)(b*S) + lr) * DP + hi*8;
    const unsigned short* vbase = vT + (size_t)lr*NROWS + (size_t)b*S + hi*8;

    f32x16 of0 = {0,0,0,0,0,0,0,0,0,0,0,0,0,0,0,0};
    f32x16 of1 = {0,0,0,0,0,0,0,0,0,0,0,0,0,0,0,0};
    float el = 0.f;

    const int bb = 127 - w*32 - lr + 4*hi;

    bf16x8 kfA[3], vfA[4], kfB[3], vfB[4];

    auto loadK = [&](int kt, bf16x8* kf) {
        const unsigned short* p = kbase + (size_t)kt*DP;
        kf[0] = ldfrag(p); kf[1] = ldfrag(p + 16); kf[2] = ldfrag(p + 32);
    };
    auto loadV = [&](int kt, bf16x8* vf) {
        const unsigned short* p = vbase + kt;
        vf[0] = ldfrag(p);
        vf[1] = ldfrag(p + 16);
        vf[2] = ldfrag(p + (size_t)32*NROWS);
        vf[3] = ldfrag(p + (size_t)32*NROWS + 16);
    };

    auto compute = [&](int ktl, const bf16x8* kf, const bf16x8* vf) {
        f32x16 c = {0,0,0,0,0,0,0,0,0,0,0,0,0,0,0,0};
        c = __builtin_amdgcn_mfma_f32_32x32x16_bf16(kf[0], qf0, c, 0,0,0);
        c = __builtin_amdgcn_mfma_f32_32x32x16_bf16(kf[1], qf1, c, 0,0,0);
        c = __builtin_amdgcn_mfma_f32_32x32x16_bf16(kf[2], qf2, c, 0,0,0);

        float e[16];
        #pragma unroll
        for (int r = 0; r < 16; ++r) {
            float s = c[r] + sbtw[bb + ktl + (r&3) + 8*(r>>2)];
            e[r] = __expf(s);
            el += e[r];
        }
        unsigned a0 = cvtpk(e[0],  e[1]);
        unsigned a1 = cvtpk(e[2],  e[3]);
        unsigned a2 = cvtpk(e[4],  e[5]);
        unsigned a3 = cvtpk(e[6],  e[7]);
        plswap(a0, a2);
        plswap(a1, a3);
        unsigned b0 = cvtpk(e[8],  e[9]);
        unsigned b1 = cvtpk(e[10], e[11]);
        unsigned b2 = cvtpk(e[12], e[13]);
        unsigned b3 = cvtpk(e[14], e[15]);
        plswap(b0, b2);
        plswap(b1, b3);
        uint4 u0 = {a0, a1, a2, a3};
        uint4 u1 = {b0, b1, b2, b3};
        bf16x8 pa0 = __builtin_bit_cast(bf16x8, u0);
        bf16x8 pa1 = __builtin_bit_cast(bf16x8, u1);

        of0 = __builtin_amdgcn_mfma_f32_32x32x16_bf16(pa0, vf[0], of0, 0,0,0);
        of0 = __builtin_amdgcn_mfma_f32_32x32x16_bf16(pa1, vf[1], of0, 0,0,0);
        of1 = __builtin_amdgcn_mfma_f32_32x32x16_bf16(pa0, vf[2], of1, 0,0,0);
        of1 = __builtin_amdgcn_mfma_f32_32x32x16_bf16(pa1, vf[3], of1, 0,0,0);
    };

    loadK(kt0, kfA); loadV(kt0, vfA);
    for (int kt = kt0; kt < kt0 + klen; kt += 64) {
        loadK(kt+32, kfB); loadV(kt+32, vfB);
        compute(kt - kt0, kfA, vfA);
        if (kt + 64 < kt0 + klen) { loadK(kt+64, kfA); loadV(kt+64, vfA); }
        compute(kt + 32 - kt0, kfB, vfB);
    }

    el += __shfl_xor(el, 32);

    const size_t rowbase = (size_t)blockIdx.z * NROWS + b*S + q0;
    #pragma unroll
    for (int r = 0; r < 16; ++r) {
        int qr = (r&3) + 8*(r>>2) + 4*hi;
        float* pr = po + (rowbase + qr) * D;
        pr[lr] = of0[r];
        if (lr < 8) pr[32 + lr] = of1[r];
    }
    if (hi == 0) pl[rowbase + lr] = el;
}

// ---------------- Kernel 4: split-K combine + O-proj + residual + FF + rmsnorm ----------------
// 2048 blocks, 8 rows/block; weights direct from global (L1/L2-resident).
__global__ __launch_bounds__(256) void k4_out_ff(
    const unsigned short* __restrict__ xb, const float* __restrict__ po, const float* __restrict__ pl,
    const float* __restrict__ Wo, const float* __restrict__ ln2,
    const float* __restrict__ wi, const float* __restrict__ wo,
    const float* __restrict__ lnf, float* __restrict__ out, int nsplit)
{
    __shared__ float sA[4][D], sB2[4][D];

    int tid = threadIdx.x;
    int wave = tid >> 6, lane = tid & 63;
    int base = blockIdx.x * 8;

    for (int it = 0; it < 2; ++it) {
        int row = base + it*4 + wave;

        float lsum = 0.f;
        for (int s = 0; s < nsplit; ++s) lsum += pl[(size_t)s*NROWS + row];
        float linv = 1.0f / lsum;
        if (lane < D) {
            float acc = 0.f;
            for (int s = 0; s < nsplit; ++s) acc += po[((size_t)s*NROWS + row)*D + lane];
            sA[wave][lane] = acc * linv;
        }

        float x2 = 0.f;
        if (lane < D) {
            float a0=0.f,a1=0.f,a2=0.f,a3=0.f;
            const float4* a4 = (const float4*)&sA[wave][0];
            #pragma unroll
            for (int i = 0; i < D/4; ++i) {
                float4 a = a4[i];
                a0 += a.x*Wo[(4*i+0)*D+lane];
                a1 += a.y*Wo[(4*i+1)*D+lane];
                a2 += a.z*Wo[(4*i+2)*D+lane];
                a3 += a.w*Wo[(4*i+3)*D+lane];
            }
            x2 = bf2f(xb[(size_t)row*XSTR + lane]) + (a0+a1) + (a2+a3);
        }
        float ss = x2 * x2;
        #pragma unroll
        for (int off = 32; off; off >>= 1) ss += __shfl_down(ss, off);
        ss = __shfl(ss, 0);
        float inv = rsqrtf(ss * (1.0f/D) + 1e-6f);
        if (lane < D) sB2[wave][lane] = x2 * inv * ln2[lane];

        float f1 = 0.f;
        if (lane < D) {
            float a0=0.f,a1=0.f,a2=0.f,a3=0.f;
            const float4* b4 = (const float4*)&sB2[wave][0];
            #pragma unroll
            for (int i = 0; i < D/4; ++i) {
                float4 h = b4[i];
                a0 += h.x*wi[(4*i+0)*D+lane];
                a1 += h.y*wi[(4*i+1)*D+lane];
                a2 += h.z*wi[(4*i+2)*D+lane];
                a3 += h.w*wi[(4*i+3)*D+lane];
            }
            f1 = fmaxf((a0+a1) + (a2+a3), 0.f);
            sA[wave][lane] = f1;
        }

        float x3 = 0.f;
        if (lane < D) {
            float a0=0.f,a1=0.f,a2=0.f,a3=0.f;
            const float4* a4 = (const float4*)&sA[wave][0];
            #pragma unroll
            for (int i = 0; i < D/4; ++i) {
                float4 h = a4[i];
                a0 += h.x*wo[(4*i+0)*D+lane];
                a1 += h.y*wo[(4*i+1)*D+lane];
                a2 += h.z*wo[(4*i+2)*D+lane];
                a3 += h.w*wo[(4*i+3)*D+lane];
            }
            x3 = x2 + (a0+a1) + (a2+a3);
        }
        float ss2 = x3 * x3;
        #pragma unroll
        for (int off = 32; off; off >>= 1) ss2 += __shfl_down(ss2, off);
        ss2 = __shfl(ss2, 0);
        float inv2 = rsqrtf(ss2 * (1.0f/D) + 1e-6f);
        if (lane < D) out[row*D + lane] = x3 * inv2 * lnf[lane];
    }
}

extern "C" void kernel_launch(void* const* d_in, const int* in_sizes, int n_in,
                              void* d_out, int out_size, void* d_ws, size_t ws_size,
                              hipStream_t stream) {
    const float* embs = (const float*)d_in[0];
    const float* Wa   = (const float*)d_in[1];
    const float* ba   = (const float*)d_in[2];
    const float* ln1  = (const float*)d_in[3];
    const float* Wq   = (const float*)d_in[4];
    const float* Wk   = (const float*)d_in[5];
    const float* Wv   = (const float*)d_in[6];
    const float* Wo   = (const float*)d_in[7];
    const float* ln2  = (const float*)d_in[8];
    const float* wi   = (const float*)d_in[9];
    const float* wo   = (const float*)d_in[10];
    const float* lnf  = (const float*)d_in[11];
    const float* rb   = (const float*)d_in[12];

    char* wsb = (char*)d_ws;
    unsigned short* xb  = (unsigned short*)(wsb);              // NROWS*48*2 = 1,572,864
    unsigned short* qb  = (unsigned short*)(wsb + 1572864);    // NROWS*64*2 = 2,097,152
    unsigned short* kbq = (unsigned short*)(wsb + 3670016);    // 2,097,152
    unsigned short* vT  = (unsigned short*)(wsb + 5767168);    // 2,097,152
    unsigned short* waT = (unsigned short*)(wsb + 7864320);    // 64*144*2 = 18,432
    unsigned short* wqT = (unsigned short*)(wsb + 7882752);    // 64*48*2 = 6,144
    unsigned short* wkT = (unsigned short*)(wsb + 7888896);
    unsigned short* wvT = (unsigned short*)(wsb + 7895040);
    // po/pl/btab from 7,901,184

    int nsplit = 4;
    while (nsplit > 1 &&
           (size_t)7901184 + (size_t)nsplit*(2621440 + 65536) + 16384 > ws_size)
        nsplit >>= 1;
    float* po   = (float*)(wsb + 7901184);
    float* pl   = (float*)(wsb + 7901184 + (size_t)nsplit*2621440);
    float* btab = (float*)(wsb + 7901184 + (size_t)nsplit*(2621440 + 65536));
    int klen = S / nsplit;

    // zero V-pad rows d=40..63 (vT written only for d<40 by k1)
    (void)hipMemsetAsync(vT + (size_t)D*NROWS, 0, (size_t)(DVP - D)*NROWS*2, stream);

    k0_prep<<<36, 256, 0, stream>>>(Wa, ba, ln1, Wq, Wk, Wv, waT, wqT, wkT, wvT);
    k1_adapter_qkv<<<NROWS/32, 64, 0, stream>>>(embs, waT, wqT, wkT, wvT, xb, qb, kbq, vT);
    k2_bias_table<<<16, 256, 0, stream>>>(rb, btab);
    k3_attn_mfma<<<dim3(S/128, B, nsplit), 256, 0, stream>>>(qb, kbq, vT, btab, po, pl, klen);
    k4_out_ff<<<NROWS/8, 256, 0, stream>>>(xb, po, pl, Wo, ln2, wi, wo, lnf, (float*)d_out, nsplit);
}

// Round 7
// 61.019 us; speedup vs baseline: 2.3617x; 1.5131x over previous
//
#include <hip/hip_runtime.h>
#include <hip/hip_bf16.h>
#include <math.h>

#define D 40
#define DIN 128
#define S 2048
#define B 8
#define NROWS (B*S)   // 16384
#define DP 64         // padded depth for Q/K bf16 rows
#define DVP 64        // padded depth (rows) for transposed V
#define XSTR 48       // xb row stride (ushorts)

typedef __bf16 bf16x8 __attribute__((ext_vector_type(8)));
typedef float f32x4 __attribute__((ext_vector_type(4)));
typedef float f32x16 __attribute__((ext_vector_type(16)));

static __device__ __forceinline__ unsigned short f2bf(float f) {
    unsigned u = __builtin_bit_cast(unsigned, f);
    u += 0x7fff + ((u >> 16) & 1);   // RNE
    return (unsigned short)(u >> 16);
}
static __device__ __forceinline__ float bf2f(unsigned short h) {
    return __builtin_bit_cast(float, (unsigned)h << 16);
}
static __device__ __forceinline__ bf16x8 ldfrag(const unsigned short* p) {
    return __builtin_bit_cast(bf16x8, *(const uint4*)p);
}
static __device__ __forceinline__ unsigned cvtpk(float lo, float hi) {
    unsigned r;
    asm("v_cvt_pk_bf16_f32 %0, %1, %2" : "=v"(r) : "v"(lo), "v"(hi));
    return r;
}
static __device__ __forceinline__ void plswap(unsigned &a, unsigned &b) {
    asm("v_permlane32_swap_b32 %0, %1" : "+v"(a), "+v"(b));
}

// ---------------- Kernel 0: weight prep (bf16 transposes, folds) ----------------
// waT[col][k]: k<128 -> Wa[k][col]; k==128 -> ba[col]; else 0. col>=40 -> 0.
// w{q,k,v}T[col][d] = W[d][col] * ln1[d]; woT[col][d] = Wo[d][col];
// wiT[col][d] = wi[d][col] * ln2[d];      wo2T[col][d] = wo[d][col].
__global__ __launch_bounds__(256) void k0_prep(
    const float* __restrict__ Wa, const float* __restrict__ ba, const float* __restrict__ ln1,
    const float* __restrict__ Wq, const float* __restrict__ Wk, const float* __restrict__ Wv,
    const float* __restrict__ Wo, const float* __restrict__ ln2,
    const float* __restrict__ wi, const float* __restrict__ wo,
    unsigned short* __restrict__ waT, unsigned short* __restrict__ wqT,
    unsigned short* __restrict__ wkT, unsigned short* __restrict__ wvT,
    unsigned short* __restrict__ woT, unsigned short* __restrict__ wiT,
    unsigned short* __restrict__ wo2T)
{
    int i = blockIdx.x * 256 + threadIdx.x;
    if (i < 64*144) {
        int col = i / 144, k = i - col*144;
        float v = 0.f;
        if (col < D) {
            if (k < DIN) v = Wa[k*D + col];
            else if (k == DIN) v = ba[col];
        }
        waT[i] = f2bf(v);
    }
    if (i < 64*48) {
        int col = i / 48, d = i - col*48;
        bool ok = (col < D && d < D);
        float s1 = ok ? ln1[d] : 0.f;
        float s2 = ok ? ln2[d] : 0.f;
        wqT[i]  = f2bf(ok ? Wq[d*D + col] * s1 : 0.f);
        wkT[i]  = f2bf(ok ? Wk[d*D + col] * s1 : 0.f);
        wvT[i]  = f2bf(ok ? Wv[d*D + col] * s1 : 0.f);
        woT[i]  = f2bf(ok ? Wo[d*D + col]      : 0.f);
        wiT[i]  = f2bf(ok ? wi[d*D + col] * s2 : 0.f);
        wo2T[i] = f2bf(ok ? wo[d*D + col]      : 0.f);
    }
}

// C-layout -> row-major bf16 frags (validated in k1/k3):
// u0 = cols hi*8+0..7 (base 0), u1 = base 16, u2 = base 32.
static __device__ __forceinline__ void repack_cl(
    const f32x16& t0, const f32x16& t1, uint4& u0, uint4& u1, uint4& u2)
{
    unsigned a0=cvtpk(t0[0],t0[1]),  a1=cvtpk(t0[2],t0[3]),
             a2=cvtpk(t0[4],t0[5]),  a3=cvtpk(t0[6],t0[7]);
    plswap(a0,a2); plswap(a1,a3);
    unsigned b0=cvtpk(t0[8],t0[9]),  b1=cvtpk(t0[10],t0[11]),
             b2=cvtpk(t0[12],t0[13]),b3=cvtpk(t0[14],t0[15]);
    plswap(b0,b2); plswap(b1,b3);
    unsigned c0=cvtpk(t1[0],t1[1]),  c1=cvtpk(t1[2],t1[3]),
             c2=cvtpk(t1[4],t1[5]),  c3=cvtpk(t1[6],t1[7]);
    plswap(c0,c2); plswap(c1,c3);
    u0 = (uint4){a0,a1,a2,a3}; u1 = (uint4){b0,b1,b2,b3}; u2 = (uint4){c0,c1,c2,c3};
}

// ---------------- Kernel 1: adapter + rmsnorm + QKV, all-MFMA ----------------
__global__ __launch_bounds__(64) void k1_adapter_qkv(
    const float* __restrict__ embs,
    const unsigned short* __restrict__ waT, const unsigned short* __restrict__ wqT,
    const unsigned short* __restrict__ wkT, const unsigned short* __restrict__ wvT,
    unsigned short* __restrict__ xb, unsigned short* __restrict__ qb,
    unsigned short* __restrict__ kbq, unsigned short* __restrict__ vT)
{
    const int l  = threadIdx.x;
    const int lr = l & 31, hi = l >> 5;
    const int row = blockIdx.x * 32 + lr;

    const float* erow = embs + (size_t)row * DIN;
    bf16x8 eb[9];
    #pragma unroll
    for (int kk = 0; kk < 8; ++kk) {
        float4 f0 = *(const float4*)(erow + kk*16 + hi*8);
        float4 f1 = *(const float4*)(erow + kk*16 + hi*8 + 4);
        uint4 u = { cvtpk(f0.x, f0.y), cvtpk(f0.z, f0.w),
                    cvtpk(f1.x, f1.y), cvtpk(f1.z, f1.w) };
        eb[kk] = __builtin_bit_cast(bf16x8, u);
    }
    {
        uint4 u = { hi == 0 ? 0x3f80u : 0u, 0u, 0u, 0u };
        eb[8] = __builtin_bit_cast(bf16x8, u);
    }

    f32x16 x0 = {0,0,0,0,0,0,0,0,0,0,0,0,0,0,0,0};
    f32x16 x1 = {0,0,0,0,0,0,0,0,0,0,0,0,0,0,0,0};
    #pragma unroll
    for (int kk = 0; kk < 9; ++kk) {
        bf16x8 a0 = ldfrag(waT + lr*144      + kk*16 + hi*8);
        bf16x8 a1 = ldfrag(waT + (32+lr)*144 + kk*16 + hi*8);
        x0 = __builtin_amdgcn_mfma_f32_32x32x16_bf16(a0, eb[kk], x0, 0,0,0);
        x1 = __builtin_amdgcn_mfma_f32_32x32x16_bf16(a1, eb[kk], x1, 0,0,0);
    }

    float ss = 0.f;
    #pragma unroll
    for (int r = 0; r < 16; ++r) {
        x0[r] = fmaxf(x0[r], 0.f);
        x1[r] = fmaxf(x1[r], 0.f);
        ss += x0[r]*x0[r] + x1[r]*x1[r];
    }
    ss += __shfl_xor(ss, 32);
    const float inv = rsqrtf(ss * (1.0f/D) + 1e-6f);

    {
        uint4 u0,u1,u2; repack_cl(x0, x1, u0, u1, u2);
        unsigned short* p = xb + (size_t)row*XSTR;
        *(uint4*)(p + hi*8)      = u0;
        *(uint4*)(p + 16 + hi*8) = u1;
        *(uint4*)(p + 32 + hi*8) = u2;
    }

    #pragma unroll
    for (int r = 0; r < 16; ++r) { x0[r] *= inv; x1[r] *= inv; }
    uint4 h0,h1,h2; repack_cl(x0, x1, h0, h1, h2);
    bf16x8 hb[3] = { __builtin_bit_cast(bf16x8, h0),
                     __builtin_bit_cast(bf16x8, h1),
                     __builtin_bit_cast(bf16x8, h2) };

    f32x16 qa0={0,0,0,0,0,0,0,0,0,0,0,0,0,0,0,0}, qa1={0,0,0,0,0,0,0,0,0,0,0,0,0,0,0,0};
    f32x16 ka0={0,0,0,0,0,0,0,0,0,0,0,0,0,0,0,0}, ka1={0,0,0,0,0,0,0,0,0,0,0,0,0,0,0,0};
    f32x16 va0={0,0,0,0,0,0,0,0,0,0,0,0,0,0,0,0}, va1={0,0,0,0,0,0,0,0,0,0,0,0,0,0,0,0};
    #pragma unroll
    for (int t = 0; t < 3; ++t) {
        bf16x8 h = hb[t];
        qa0 = __builtin_amdgcn_mfma_f32_32x32x16_bf16(ldfrag(wqT + lr*48      + t*16 + hi*8), h, qa0, 0,0,0);
        qa1 = __builtin_amdgcn_mfma_f32_32x32x16_bf16(ldfrag(wqT + (32+lr)*48 + t*16 + hi*8), h, qa1, 0,0,0);
        ka0 = __builtin_amdgcn_mfma_f32_32x32x16_bf16(ldfrag(wkT + lr*48      + t*16 + hi*8), h, ka0, 0,0,0);
        ka1 = __builtin_amdgcn_mfma_f32_32x32x16_bf16(ldfrag(wkT + (32+lr)*48 + t*16 + hi*8), h, ka1, 0,0,0);
        va0 = __builtin_amdgcn_mfma_f32_32x32x16_bf16(ldfrag(wvT + lr*48      + t*16 + hi*8), h, va0, 0,0,0);
        va1 = __builtin_amdgcn_mfma_f32_32x32x16_bf16(ldfrag(wvT + (32+lr)*48 + t*16 + hi*8), h, va1, 0,0,0);
    }

    {
        uint4 u0,u1,u2; repack_cl(qa0, qa1, u0, u1, u2);
        unsigned short* p = qb + (size_t)row*DP;
        *(uint4*)(p + hi*8) = u0; *(uint4*)(p + 16 + hi*8) = u1; *(uint4*)(p + 32 + hi*8) = u2;
    }
    {
        uint4 u0,u1,u2; repack_cl(ka0, ka1, u0, u1, u2);
        unsigned short* p = kbq + (size_t)row*DP;
        *(uint4*)(p + hi*8) = u0; *(uint4*)(p + 16 + hi*8) = u1; *(uint4*)(p + 32 + hi*8) = u2;
    }
    #pragma unroll
    for (int r = 0; r < 16; ++r) {
        int col = (r&3) + 8*(r>>2) + 4*hi;
        vT[(size_t)col*NROWS + row] = f2bf(va0[r]);
        if (r < 4) vT[(size_t)(32 + (r&3) + 4*hi)*NROWS + row] = f2bf(va1[r]);
    }
}

// ---------------- Kernel 2: relative-position bias table ----------------
__global__ void k2_bias_table(const float* __restrict__ rel_bias, float* __restrict__ btab)
{
    int t = blockIdx.x * 256 + threadIdx.x;
    if (t >= 2*S - 1) return;
    int rel = t - (S - 1);          // rel = k - q
    int bucket = (rel > 0) ? 16 : 0;
    int ar = rel < 0 ? -rel : rel;
    int add;
    if (ar < 8) {
        add = ar;
    } else {
        float tt = logf((float)ar * 0.125f) / logf(16.0f) * 8.0f;
        int lg = 8 + (int)tt;
        add = lg < 15 ? lg : 15;
    }
    btab[t] = rel_bias[bucket + add];
}

// ---------------- Kernel 3: flash attention, swapped-QK^T 32x32 MFMA ----------------
__global__ __launch_bounds__(256) void k3_attn_mfma(
    const unsigned short* __restrict__ qb, const unsigned short* __restrict__ kb,
    const unsigned short* __restrict__ vT, const float* __restrict__ btab,
    float* __restrict__ po, float* __restrict__ pl, int klen)
{
    __shared__ float sbtw[2176 + 16];

    const int q0blk = blockIdx.x * 128;
    const int kt0   = blockIdx.z * klen;
    const int woff  = (S-1) + kt0 - q0blk - 127;

    int tid = threadIdx.x;
    for (int i = tid; i < klen + 128; i += 256) {
        int g = woff + i;
        sbtw[i] = btab[g < 0 ? 0 : (g > 4094 ? 4094 : g)];
    }
    __syncthreads();

    const int w  = tid >> 6, l = tid & 63;
    const int lr = l & 31,  hi = l >> 5;
    const int b  = blockIdx.y;
    const int q0 = q0blk + w * 32;

    const unsigned short* qrow = qb + ((size_t)(b*S) + q0 + lr) * DP + hi*8;
    bf16x8 qf0 = ldfrag(qrow);
    bf16x8 qf1 = ldfrag(qrow + 16);
    bf16x8 qf2 = ldfrag(qrow + 32);

    const unsigned short* kbase = kb + ((size_t)(b*S) + lr) * DP + hi*8;
    const unsigned short* vbase = vT + (size_t)lr*NROWS + (size_t)b*S + hi*8;

    f32x16 of0 = {0,0,0,0,0,0,0,0,0,0,0,0,0,0,0,0};
    f32x16 of1 = {0,0,0,0,0,0,0,0,0,0,0,0,0,0,0,0};
    float el = 0.f;

    const int bb = 127 - w*32 - lr + 4*hi;

    bf16x8 kfA[3], vfA[4], kfB[3], vfB[4];

    auto loadK = [&](int kt, bf16x8* kf) {
        const unsigned short* p = kbase + (size_t)kt*DP;
        kf[0] = ldfrag(p); kf[1] = ldfrag(p + 16); kf[2] = ldfrag(p + 32);
    };
    auto loadV = [&](int kt, bf16x8* vf) {
        const unsigned short* p = vbase + kt;
        vf[0] = ldfrag(p);
        vf[1] = ldfrag(p + 16);
        vf[2] = ldfrag(p + (size_t)32*NROWS);
        vf[3] = ldfrag(p + (size_t)32*NROWS + 16);
    };

    auto compute = [&](int ktl, const bf16x8* kf, const bf16x8* vf) {
        f32x16 c = {0,0,0,0,0,0,0,0,0,0,0,0,0,0,0,0};
        c = __builtin_amdgcn_mfma_f32_32x32x16_bf16(kf[0], qf0, c, 0,0,0);
        c = __builtin_amdgcn_mfma_f32_32x32x16_bf16(kf[1], qf1, c, 0,0,0);
        c = __builtin_amdgcn_mfma_f32_32x32x16_bf16(kf[2], qf2, c, 0,0,0);

        float e[16];
        #pragma unroll
        for (int r = 0; r < 16; ++r) {
            float s = c[r] + sbtw[bb + ktl + (r&3) + 8*(r>>2)];
            e[r] = __expf(s);
            el += e[r];
        }
        unsigned a0 = cvtpk(e[0],  e[1]);
        unsigned a1 = cvtpk(e[2],  e[3]);
        unsigned a2 = cvtpk(e[4],  e[5]);
        unsigned a3 = cvtpk(e[6],  e[7]);
        plswap(a0, a2);
        plswap(a1, a3);
        unsigned b0 = cvtpk(e[8],  e[9]);
        unsigned b1 = cvtpk(e[10], e[11]);
        unsigned b2 = cvtpk(e[12], e[13]);
        unsigned b3 = cvtpk(e[14], e[15]);
        plswap(b0, b2);
        plswap(b1, b3);
        uint4 u0 = {a0, a1, a2, a3};
        uint4 u1 = {b0, b1, b2, b3};
        bf16x8 pa0 = __builtin_bit_cast(bf16x8, u0);
        bf16x8 pa1 = __builtin_bit_cast(bf16x8, u1);

        of0 = __builtin_amdgcn_mfma_f32_32x32x16_bf16(pa0, vf[0], of0, 0,0,0);
        of0 = __builtin_amdgcn_mfma_f32_32x32x16_bf16(pa1, vf[1], of0, 0,0,0);
        of1 = __builtin_amdgcn_mfma_f32_32x32x16_bf16(pa0, vf[2], of1, 0,0,0);
        of1 = __builtin_amdgcn_mfma_f32_32x32x16_bf16(pa1, vf[3], of1, 0,0,0);
    };

    loadK(kt0, kfA); loadV(kt0, vfA);
    for (int kt = kt0; kt < kt0 + klen; kt += 64) {
        loadK(kt+32, kfB); loadV(kt+32, vfB);
        compute(kt - kt0, kfA, vfA);
        if (kt + 64 < kt0 + klen) { loadK(kt+64, kfA); loadV(kt+64, vfA); }
        compute(kt + 32 - kt0, kfB, vfB);
    }

    el += __shfl_xor(el, 32);

    const size_t rowbase = (size_t)blockIdx.z * NROWS + b*S + q0;
    #pragma unroll
    for (int r = 0; r < 16; ++r) {
        int qr = (r&3) + 8*(r>>2) + 4*hi;
        float* pr = po + (rowbase + qr) * D;
        pr[lr] = of0[r];
        if (lr < 8) pr[32 + lr] = of1[r];
    }
    if (hi == 0) pl[rowbase + lr] = el;
}

// ---------------- Kernel 4: combine + O-proj + residual + FF + rmsnorm, all-MFMA ----------------
// 512 blocks x 64 threads; wave owns 32 rows. Same register algebra as k1.
__global__ __launch_bounds__(64) void k4_out_ff(
    const unsigned short* __restrict__ xb, const float* __restrict__ po,
    const float* __restrict__ pl,
    const unsigned short* __restrict__ woT, const unsigned short* __restrict__ wiT,
    const unsigned short* __restrict__ wo2T, const float* __restrict__ lnf,
    float* __restrict__ out, int nsplit)
{
    const int l  = threadIdx.x;
    const int lr = l & 31, hi = l >> 5;
    const int row = blockIdx.x * 32 + lr;

    // ---- combine split-K partials into B-fragments (a[d][row], d = t*16+hi*8+j)
    float lsum = 0.f;
    for (int s = 0; s < nsplit; ++s) lsum += pl[(size_t)s*NROWS + row];
    const float linv = 1.0f / lsum;

    float a[3][8];
    #pragma unroll
    for (int t = 0; t < 3; ++t)
        #pragma unroll
        for (int j = 0; j < 8; ++j) a[t][j] = 0.f;
    for (int s = 0; s < nsplit; ++s) {
        const float* pr = po + ((size_t)s*NROWS + row)*D;
        #pragma unroll
        for (int t = 0; t < 3; ++t) {
            if (t == 2 && hi == 1) continue;          // d = 40..47 out of range
            float4 f0 = *(const float4*)(pr + t*16 + hi*8);
            float4 f1 = *(const float4*)(pr + t*16 + hi*8 + 4);
            a[t][0]+=f0.x; a[t][1]+=f0.y; a[t][2]+=f0.z; a[t][3]+=f0.w;
            a[t][4]+=f1.x; a[t][5]+=f1.y; a[t][6]+=f1.z; a[t][7]+=f1.w;
        }
    }
    bf16x8 ab[3];
    #pragma unroll
    for (int t = 0; t < 3; ++t) {
        uint4 u = { cvtpk(a[t][0]*linv, a[t][1]*linv), cvtpk(a[t][2]*linv, a[t][3]*linv),
                    cvtpk(a[t][4]*linv, a[t][5]*linv), cvtpk(a[t][6]*linv, a[t][7]*linv) };
        ab[t] = __builtin_bit_cast(bf16x8, u);
    }

    // ---- x2 = xres + a @ Wo (C-layout: col tiles 0..31 / 32..63)
    f32x16 c0 = {0,0,0,0,0,0,0,0,0,0,0,0,0,0,0,0};
    f32x16 c1 = {0,0,0,0,0,0,0,0,0,0,0,0,0,0,0,0};
    #pragma unroll
    for (int t = 0; t < 3; ++t) {
        c0 = __builtin_amdgcn_mfma_f32_32x32x16_bf16(ldfrag(woT + lr*48      + t*16 + hi*8), ab[t], c0, 0,0,0);
        c1 = __builtin_amdgcn_mfma_f32_32x32x16_bf16(ldfrag(woT + (32+lr)*48 + t*16 + hi*8), ab[t], c1, 0,0,0);
    }
    // residual add (chunked 4-col groups of the C mapping; pads stay exact 0)
    const unsigned short* xr = xb + (size_t)row*XSTR;
    #pragma unroll
    for (int rr = 0; rr < 4; ++rr) {
        ushort4 v = *(const ushort4*)(xr + rr*8 + 4*hi);
        c0[rr*4+0] += bf2f(v.x); c0[rr*4+1] += bf2f(v.y);
        c0[rr*4+2] += bf2f(v.z); c0[rr*4+3] += bf2f(v.w);
    }
    {
        ushort4 v = *(const ushort4*)(xr + 32 + 4*hi);
        c1[0] += bf2f(v.x); c1[1] += bf2f(v.y); c1[2] += bf2f(v.z); c1[3] += bf2f(v.w);
    }

    // ---- rmsnorm(x2) (ln2 folded into wiT)
    float ss = 0.f;
    #pragma unroll
    for (int r = 0; r < 16; ++r) ss += c0[r]*c0[r] + c1[r]*c1[r];
    ss += __shfl_xor(ss, 32);
    const float inv2 = rsqrtf(ss * (1.0f/D) + 1e-6f);

    f32x16 t0, t1;
    #pragma unroll
    for (int r = 0; r < 16; ++r) { t0[r] = c0[r]*inv2; t1[r] = c1[r]*inv2; }
    uint4 h0,h1,h2; repack_cl(t0, t1, h0, h1, h2);
    bf16x8 hb[3] = { __builtin_bit_cast(bf16x8, h0),
                     __builtin_bit_cast(bf16x8, h1),
                     __builtin_bit_cast(bf16x8, h2) };

    // ---- f = relu(h @ wi')
    f32x16 d0 = {0,0,0,0,0,0,0,0,0,0,0,0,0,0,0,0};
    f32x16 d1 = {0,0,0,0,0,0,0,0,0,0,0,0,0,0,0,0};
    #pragma unroll
    for (int t = 0; t < 3; ++t) {
        d0 = __builtin_amdgcn_mfma_f32_32x32x16_bf16(ldfrag(wiT + lr*48      + t*16 + hi*8), hb[t], d0, 0,0,0);
        d1 = __builtin_amdgcn_mfma_f32_32x32x16_bf16(ldfrag(wiT + (32+lr)*48 + t*16 + hi*8), hb[t], d1, 0,0,0);
    }
    #pragma unroll
    for (int r = 0; r < 16; ++r) { d0[r] = fmaxf(d0[r], 0.f); d1[r] = fmaxf(d1[r], 0.f); }
    uint4 g0,g1,g2; repack_cl(d0, d1, g0, g1, g2);
    bf16x8 fb[3] = { __builtin_bit_cast(bf16x8, g0),
                     __builtin_bit_cast(bf16x8, g1),
                     __builtin_bit_cast(bf16x8, g2) };

    // ---- x3 = x2 + f @ wo
    f32x16 e0 = {0,0,0,0,0,0,0,0,0,0,0,0,0,0,0,0};
    f32x16 e1 = {0,0,0,0,0,0,0,0,0,0,0,0,0,0,0,0};
    #pragma unroll
    for (int t = 0; t < 3; ++t) {
        e0 = __builtin_amdgcn_mfma_f32_32x32x16_bf16(ldfrag(wo2T + lr*48      + t*16 + hi*8), fb[t], e0, 0,0,0);
        e1 = __builtin_amdgcn_mfma_f32_32x32x16_bf16(ldfrag(wo2T + (32+lr)*48 + t*16 + hi*8), fb[t], e1, 0,0,0);
    }
    #pragma unroll
    for (int r = 0; r < 16; ++r) { e0[r] += c0[r]; e1[r] += c1[r]; }

    // ---- final rmsnorm + store (chunked float4, C mapping)
    float ss2 = 0.f;
    #pragma unroll
    for (int r = 0; r < 16; ++r) ss2 += e0[r]*e0[r] + e1[r]*e1[r];
    ss2 += __shfl_xor(ss2, 32);
    const float inv3 = rsqrtf(ss2 * (1.0f/D) + 1e-6f);

    float* orow = out + (size_t)row * D;
    #pragma unroll
    for (int rr = 0; rr < 4; ++rr) {
        float4 lf = *(const float4*)(lnf + rr*8 + 4*hi);
        float4 v = { e0[rr*4+0]*inv3*lf.x, e0[rr*4+1]*inv3*lf.y,
                     e0[rr*4+2]*inv3*lf.z, e0[rr*4+3]*inv3*lf.w };
        *(float4*)(orow + rr*8 + 4*hi) = v;
    }
    {
        float4 lf = *(const float4*)(lnf + 32 + 4*hi);
        float4 v = { e1[0]*inv3*lf.x, e1[1]*inv3*lf.y, e1[2]*inv3*lf.z, e1[3]*inv3*lf.w };
        *(float4*)(orow + 32 + 4*hi) = v;
    }
}

extern "C" void kernel_launch(void* const* d_in, const int* in_sizes, int n_in,
                              void* d_out, int out_size, void* d_ws, size_t ws_size,
                              hipStream_t stream) {
    const float* embs = (const float*)d_in[0];
    const float* Wa   = (const float*)d_in[1];
    const float* ba   = (const float*)d_in[2];
    const float* ln1  = (const float*)d_in[3];
    const float* Wq   = (const float*)d_in[4];
    const float* Wk   = (const float*)d_in[5];
    const float* Wv   = (const float*)d_in[6];
    const float* Wo   = (const float*)d_in[7];
    const float* ln2  = (const float*)d_in[8];
    const float* wi   = (const float*)d_in[9];
    const float* wo   = (const float*)d_in[10];
    const float* lnf  = (const float*)d_in[11];
    const float* rb   = (const float*)d_in[12];

    char* wsb = (char*)d_ws;
    unsigned short* xb   = (unsigned short*)(wsb);              // NROWS*48*2 = 1,572,864
    unsigned short* qb   = (unsigned short*)(wsb + 1572864);    // 2,097,152
    unsigned short* kbq  = (unsigned short*)(wsb + 3670016);    // 2,097,152
    unsigned short* vT   = (unsigned short*)(wsb + 5767168);    // 2,097,152
    unsigned short* waT  = (unsigned short*)(wsb + 7864320);    // 18,432
    unsigned short* wqT  = (unsigned short*)(wsb + 7882752);    // 6,144
    unsigned short* wkT  = (unsigned short*)(wsb + 7888896);
    unsigned short* wvT  = (unsigned short*)(wsb + 7895040);
    unsigned short* woT  = (unsigned short*)(wsb + 7901184);
    unsigned short* wiT  = (unsigned short*)(wsb + 7907328);
    unsigned short* wo2T = (unsigned short*)(wsb + 7913472);
    // po/pl/btab from 7,919,616

    int nsplit = 4;
    while (nsplit > 1 &&
           (size_t)7919616 + (size_t)nsplit*(2621440 + 65536) + 16384 > ws_size)
        nsplit >>= 1;
    float* po   = (float*)(wsb + 7919616);
    float* pl   = (float*)(wsb + 7919616 + (size_t)nsplit*2621440);
    float* btab = (float*)(wsb + 7919616 + (size_t)nsplit*(2621440 + 65536));
    int klen = S / nsplit;

    (void)hipMemsetAsync(vT + (size_t)D*NROWS, 0, (size_t)(DVP - D)*NROWS*2, stream);

    k0_prep<<<36, 256, 0, stream>>>(Wa, ba, ln1, Wq, Wk, Wv, Wo, ln2, wi, wo,
                                    waT, wqT, wkT, wvT, woT, wiT, wo2T);
    k1_adapter_qkv<<<NROWS/32, 64, 0, stream>>>(embs, waT, wqT, wkT, wvT, xb, qb, kbq, vT);
    k2_bias_table<<<16, 256, 0, stream>>>(rb, btab);
    k3_attn_mfma<<<dim3(S/128, B, nsplit), 256, 0, stream>>>(qb, kbq, vT, btab, po, pl, klen);
    k4_out_ff<<<NROWS/32, 64, 0, stream>>>(xb, po, pl, woT, wiT, wo2T, lnf, (float*)d_out, nsplit);
}

// Round 8
// 58.540 us; speedup vs baseline: 2.4618x; 1.0423x over previous
//
#include <hip/hip_runtime.h>
#include <hip/hip_bf16.h>
#include <math.h>

#define D 40
#define DIN 128
#define S 2048
#define B 8
#define NROWS (B*S)   // 16384
#define DP 64         // padded depth for Q/K bf16 rows
#define DVP 64        // padded depth (rows) for transposed V
#define XSTR 48       // xb row stride (ushorts)

typedef __bf16 bf16x8 __attribute__((ext_vector_type(8)));
typedef float f32x4 __attribute__((ext_vector_type(4)));
typedef float f32x16 __attribute__((ext_vector_type(16)));

static __device__ __forceinline__ unsigned short f2bf(float f) {
    unsigned u = __builtin_bit_cast(unsigned, f);
    u += 0x7fff + ((u >> 16) & 1);   // RNE
    return (unsigned short)(u >> 16);
}
static __device__ __forceinline__ float bf2f(unsigned short h) {
    return __builtin_bit_cast(float, (unsigned)h << 16);
}
static __device__ __forceinline__ bf16x8 ldfrag(const unsigned short* p) {
    return __builtin_bit_cast(bf16x8, *(const uint4*)p);
}
static __device__ __forceinline__ unsigned cvtpk(float lo, float hi) {
    unsigned r;
    asm("v_cvt_pk_bf16_f32 %0, %1, %2" : "=v"(r) : "v"(lo), "v"(hi));
    return r;
}
static __device__ __forceinline__ void plswap(unsigned &a, unsigned &b) {
    asm("v_permlane32_swap_b32 %0, %1" : "+v"(a), "+v"(b));
}

// ---------------- Kernel 0: weight prep + bias table (fused) ----------------
// waT[col][k]: k<128 -> Wa[k][col]; k==128 -> ba[col]; else 0. col>=40 -> 0.
// w{q,k,v}T[col][d] = W[d][col] * ln1[d]; woT[col][d] = Wo[d][col];
// wiT[col][d] = wi[d][col] * ln2[d];      wo2T[col][d] = wo[d][col].
// btab[t] = rel_bias[bucket(t - 2047)] for t in [0, 4095).
__global__ __launch_bounds__(256) void k0_prep(
    const float* __restrict__ Wa, const float* __restrict__ ba, const float* __restrict__ ln1,
    const float* __restrict__ Wq, const float* __restrict__ Wk, const float* __restrict__ Wv,
    const float* __restrict__ Wo, const float* __restrict__ ln2,
    const float* __restrict__ wi, const float* __restrict__ wo,
    const float* __restrict__ rel_bias,
    unsigned short* __restrict__ waT, unsigned short* __restrict__ wqT,
    unsigned short* __restrict__ wkT, unsigned short* __restrict__ wvT,
    unsigned short* __restrict__ woT, unsigned short* __restrict__ wiT,
    unsigned short* __restrict__ wo2T, float* __restrict__ btab)
{
    int i = blockIdx.x * 256 + threadIdx.x;
    if (i < 64*144) {
        int col = i / 144, k = i - col*144;
        float v = 0.f;
        if (col < D) {
            if (k < DIN) v = Wa[k*D + col];
            else if (k == DIN) v = ba[col];
        }
        waT[i] = f2bf(v);
    }
    if (i < 64*48) {
        int col = i / 48, d = i - col*48;
        bool ok = (col < D && d < D);
        float s1 = ok ? ln1[d] : 0.f;
        float s2 = ok ? ln2[d] : 0.f;
        wqT[i]  = f2bf(ok ? Wq[d*D + col] * s1 : 0.f);
        wkT[i]  = f2bf(ok ? Wk[d*D + col] * s1 : 0.f);
        wvT[i]  = f2bf(ok ? Wv[d*D + col] * s1 : 0.f);
        woT[i]  = f2bf(ok ? Wo[d*D + col]      : 0.f);
        wiT[i]  = f2bf(ok ? wi[d*D + col] * s2 : 0.f);
        wo2T[i] = f2bf(ok ? wo[d*D + col]      : 0.f);
    }
    if (i < 2*S - 1) {
        int rel = i - (S - 1);          // rel = k - q
        int bucket = (rel > 0) ? 16 : 0;
        int ar = rel < 0 ? -rel : rel;
        int add;
        if (ar < 8) {
            add = ar;
        } else {
            float tt = logf((float)ar * 0.125f) / logf(16.0f) * 8.0f;
            int lg = 8 + (int)tt;
            add = lg < 15 ? lg : 15;
        }
        btab[i] = rel_bias[bucket + add];
    }
}

// C-layout -> row-major bf16 frags (validated in k1/k3):
// u0 = cols hi*8+0..7 (base 0), u1 = base 16, u2 = base 32.
static __device__ __forceinline__ void repack_cl(
    const f32x16& t0, const f32x16& t1, uint4& u0, uint4& u1, uint4& u2)
{
    unsigned a0=cvtpk(t0[0],t0[1]),  a1=cvtpk(t0[2],t0[3]),
             a2=cvtpk(t0[4],t0[5]),  a3=cvtpk(t0[6],t0[7]);
    plswap(a0,a2); plswap(a1,a3);
    unsigned b0=cvtpk(t0[8],t0[9]),  b1=cvtpk(t0[10],t0[11]),
             b2=cvtpk(t0[12],t0[13]),b3=cvtpk(t0[14],t0[15]);
    plswap(b0,b2); plswap(b1,b3);
    unsigned c0=cvtpk(t1[0],t1[1]),  c1=cvtpk(t1[2],t1[3]),
             c2=cvtpk(t1[4],t1[5]),  c3=cvtpk(t1[6],t1[7]);
    plswap(c0,c2); plswap(c1,c3);
    u0 = (uint4){a0,a1,a2,a3}; u1 = (uint4){b0,b1,b2,b3}; u2 = (uint4){c0,c1,c2,c3};
}

// ---------------- Kernel 1: adapter + rmsnorm + QKV, all-MFMA ----------------
__global__ __launch_bounds__(64) void k1_adapter_qkv(
    const float* __restrict__ embs,
    const unsigned short* __restrict__ waT, const unsigned short* __restrict__ wqT,
    const unsigned short* __restrict__ wkT, const unsigned short* __restrict__ wvT,
    unsigned short* __restrict__ xb, unsigned short* __restrict__ qb,
    unsigned short* __restrict__ kbq, unsigned short* __restrict__ vT)
{
    const int l  = threadIdx.x;
    const int lr = l & 31, hi = l >> 5;
    const int row = blockIdx.x * 32 + lr;

    const float* erow = embs + (size_t)row * DIN;
    bf16x8 eb[9];
    #pragma unroll
    for (int kk = 0; kk < 8; ++kk) {
        float4 f0 = *(const float4*)(erow + kk*16 + hi*8);
        float4 f1 = *(const float4*)(erow + kk*16 + hi*8 + 4);
        uint4 u = { cvtpk(f0.x, f0.y), cvtpk(f0.z, f0.w),
                    cvtpk(f1.x, f1.y), cvtpk(f1.z, f1.w) };
        eb[kk] = __builtin_bit_cast(bf16x8, u);
    }
    {
        uint4 u = { hi == 0 ? 0x3f80u : 0u, 0u, 0u, 0u };
        eb[8] = __builtin_bit_cast(bf16x8, u);
    }

    f32x16 x0 = {0,0,0,0,0,0,0,0,0,0,0,0,0,0,0,0};
    f32x16 x1 = {0,0,0,0,0,0,0,0,0,0,0,0,0,0,0,0};
    #pragma unroll
    for (int kk = 0; kk < 9; ++kk) {
        bf16x8 a0 = ldfrag(waT + lr*144      + kk*16 + hi*8);
        bf16x8 a1 = ldfrag(waT + (32+lr)*144 + kk*16 + hi*8);
        x0 = __builtin_amdgcn_mfma_f32_32x32x16_bf16(a0, eb[kk], x0, 0,0,0);
        x1 = __builtin_amdgcn_mfma_f32_32x32x16_bf16(a1, eb[kk], x1, 0,0,0);
    }

    float ss = 0.f;
    #pragma unroll
    for (int r = 0; r < 16; ++r) {
        x0[r] = fmaxf(x0[r], 0.f);
        x1[r] = fmaxf(x1[r], 0.f);
        ss += x0[r]*x0[r] + x1[r]*x1[r];
    }
    ss += __shfl_xor(ss, 32);
    const float inv = rsqrtf(ss * (1.0f/D) + 1e-6f);

    {
        uint4 u0,u1,u2; repack_cl(x0, x1, u0, u1, u2);
        unsigned short* p = xb + (size_t)row*XSTR;
        *(uint4*)(p + hi*8)      = u0;
        *(uint4*)(p + 16 + hi*8) = u1;
        *(uint4*)(p + 32 + hi*8) = u2;
    }

    #pragma unroll
    for (int r = 0; r < 16; ++r) { x0[r] *= inv; x1[r] *= inv; }
    uint4 h0,h1,h2; repack_cl(x0, x1, h0, h1, h2);
    bf16x8 hb[3] = { __builtin_bit_cast(bf16x8, h0),
                     __builtin_bit_cast(bf16x8, h1),
                     __builtin_bit_cast(bf16x8, h2) };

    f32x16 qa0={0,0,0,0,0,0,0,0,0,0,0,0,0,0,0,0}, qa1={0,0,0,0,0,0,0,0,0,0,0,0,0,0,0,0};
    f32x16 ka0={0,0,0,0,0,0,0,0,0,0,0,0,0,0,0,0}, ka1={0,0,0,0,0,0,0,0,0,0,0,0,0,0,0,0};
    f32x16 va0={0,0,0,0,0,0,0,0,0,0,0,0,0,0,0,0}, va1={0,0,0,0,0,0,0,0,0,0,0,0,0,0,0,0};
    #pragma unroll
    for (int t = 0; t < 3; ++t) {
        bf16x8 h = hb[t];
        qa0 = __builtin_amdgcn_mfma_f32_32x32x16_bf16(ldfrag(wqT + lr*48      + t*16 + hi*8), h, qa0, 0,0,0);
        qa1 = __builtin_amdgcn_mfma_f32_32x32x16_bf16(ldfrag(wqT + (32+lr)*48 + t*16 + hi*8), h, qa1, 0,0,0);
        ka0 = __builtin_amdgcn_mfma_f32_32x32x16_bf16(ldfrag(wkT + lr*48      + t*16 + hi*8), h, ka0, 0,0,0);
        ka1 = __builtin_amdgcn_mfma_f32_32x32x16_bf16(ldfrag(wkT + (32+lr)*48 + t*16 + hi*8), h, ka1, 0,0,0);
        va0 = __builtin_amdgcn_mfma_f32_32x32x16_bf16(ldfrag(wvT + lr*48      + t*16 + hi*8), h, va0, 0,0,0);
        va1 = __builtin_amdgcn_mfma_f32_32x32x16_bf16(ldfrag(wvT + (32+lr)*48 + t*16 + hi*8), h, va1, 0,0,0);
    }

    {
        uint4 u0,u1,u2; repack_cl(qa0, qa1, u0, u1, u2);
        unsigned short* p = qb + (size_t)row*DP;
        *(uint4*)(p + hi*8) = u0; *(uint4*)(p + 16 + hi*8) = u1; *(uint4*)(p + 32 + hi*8) = u2;
    }
    {
        uint4 u0,u1,u2; repack_cl(ka0, ka1, u0, u1, u2);
        unsigned short* p = kbq + (size_t)row*DP;
        *(uint4*)(p + hi*8) = u0; *(uint4*)(p + 16 + hi*8) = u1; *(uint4*)(p + 32 + hi*8) = u2;
    }
    #pragma unroll
    for (int r = 0; r < 16; ++r) {
        int col = (r&3) + 8*(r>>2) + 4*hi;
        vT[(size_t)col*NROWS + row] = f2bf(va0[r]);
        if (r < 4) vT[(size_t)(32 + (r&3) + 4*hi)*NROWS + row] = f2bf(va1[r]);
    }
    // zero pad rows d=40..63 (replaces the hipMemsetAsync dispatch)
    #pragma unroll
    for (int c = 0; c < 12; ++c) {
        vT[(size_t)(D + 2*c + hi)*NROWS + row] = 0;
    }
}

// ---------------- Kernel 3: flash attention, swapped-QK^T 32x32 MFMA ----------------
__global__ __launch_bounds__(256) void k3_attn_mfma(
    const unsigned short* __restrict__ qb, const unsigned short* __restrict__ kb,
    const unsigned short* __restrict__ vT, const float* __restrict__ btab,
    float* __restrict__ po, float* __restrict__ pl, int klen)
{
    __shared__ float sbtw[2176 + 16];

    const int q0blk = blockIdx.x * 128;
    const int kt0   = blockIdx.z * klen;
    const int woff  = (S-1) + kt0 - q0blk - 127;

    int tid = threadIdx.x;
    for (int i = tid; i < klen + 128; i += 256) {
        int g = woff + i;
        sbtw[i] = btab[g < 0 ? 0 : (g > 4094 ? 4094 : g)];
    }
    __syncthreads();

    const int w  = tid >> 6, l = tid & 63;
    const int lr = l & 31,  hi = l >> 5;
    const int b  = blockIdx.y;
    const int q0 = q0blk + w * 32;

    const unsigned short* qrow = qb + ((size_t)(b*S) + q0 + lr) * DP + hi*8;
    bf16x8 qf0 = ldfrag(qrow);
    bf16x8 qf1 = ldfrag(qrow + 16);
    bf16x8 qf2 = ldfrag(qrow + 32);

    const unsigned short* kbase = kb + ((size_t)(b*S) + lr) * DP + hi*8;
    const unsigned short* vbase = vT + (size_t)lr*NROWS + (size_t)b*S + hi*8;

    f32x16 of0 = {0,0,0,0,0,0,0,0,0,0,0,0,0,0,0,0};
    f32x16 of1 = {0,0,0,0,0,0,0,0,0,0,0,0,0,0,0,0};
    float el = 0.f;

    const int bb = 127 - w*32 - lr + 4*hi;

    bf16x8 kfA[3], vfA[4], kfB[3], vfB[4];

    auto loadK = [&](int kt, bf16x8* kf) {
        const unsigned short* p = kbase + (size_t)kt*DP;
        kf[0] = ldfrag(p); kf[1] = ldfrag(p + 16); kf[2] = ldfrag(p + 32);
    };
    auto loadV = [&](int kt, bf16x8* vf) {
        const unsigned short* p = vbase + kt;
        vf[0] = ldfrag(p);
        vf[1] = ldfrag(p + 16);
        vf[2] = ldfrag(p + (size_t)32*NROWS);
        vf[3] = ldfrag(p + (size_t)32*NROWS + 16);
    };

    auto compute = [&](int ktl, const bf16x8* kf, const bf16x8* vf) {
        f32x16 c = {0,0,0,0,0,0,0,0,0,0,0,0,0,0,0,0};
        c = __builtin_amdgcn_mfma_f32_32x32x16_bf16(kf[0], qf0, c, 0,0,0);
        c = __builtin_amdgcn_mfma_f32_32x32x16_bf16(kf[1], qf1, c, 0,0,0);
        c = __builtin_amdgcn_mfma_f32_32x32x16_bf16(kf[2], qf2, c, 0,0,0);

        float e[16];
        #pragma unroll
        for (int r = 0; r < 16; ++r) {
            float s = c[r] + sbtw[bb + ktl + (r&3) + 8*(r>>2)];
            e[r] = __expf(s);
            el += e[r];
        }
        unsigned a0 = cvtpk(e[0],  e[1]);
        unsigned a1 = cvtpk(e[2],  e[3]);
        unsigned a2 = cvtpk(e[4],  e[5]);
        unsigned a3 = cvtpk(e[6],  e[7]);
        plswap(a0, a2);
        plswap(a1, a3);
        unsigned b0 = cvtpk(e[8],  e[9]);
        unsigned b1 = cvtpk(e[10], e[11]);
        unsigned b2 = cvtpk(e[12], e[13]);
        unsigned b3 = cvtpk(e[14], e[15]);
        plswap(b0, b2);
        plswap(b1, b3);
        uint4 u0 = {a0, a1, a2, a3};
        uint4 u1 = {b0, b1, b2, b3};
        bf16x8 pa0 = __builtin_bit_cast(bf16x8, u0);
        bf16x8 pa1 = __builtin_bit_cast(bf16x8, u1);

        of0 = __builtin_amdgcn_mfma_f32_32x32x16_bf16(pa0, vf[0], of0, 0,0,0);
        of0 = __builtin_amdgcn_mfma_f32_32x32x16_bf16(pa1, vf[1], of0, 0,0,0);
        of1 = __builtin_amdgcn_mfma_f32_32x32x16_bf16(pa0, vf[2], of1, 0,0,0);
        of1 = __builtin_amdgcn_mfma_f32_32x32x16_bf16(pa1, vf[3], of1, 0,0,0);
    };

    loadK(kt0, kfA); loadV(kt0, vfA);
    for (int kt = kt0; kt < kt0 + klen; kt += 64) {
        loadK(kt+32, kfB); loadV(kt+32, vfB);
        compute(kt - kt0, kfA, vfA);
        if (kt + 64 < kt0 + klen) { loadK(kt+64, kfA); loadV(kt+64, vfA); }
        compute(kt + 32 - kt0, kfB, vfB);
    }

    el += __shfl_xor(el, 32);

    const size_t rowbase = (size_t)blockIdx.z * NROWS + b*S + q0;
    #pragma unroll
    for (int r = 0; r < 16; ++r) {
        int qr = (r&3) + 8*(r>>2) + 4*hi;
        float* pr = po + (rowbase + qr) * D;
        pr[lr] = of0[r];
        if (lr < 8) pr[32 + lr] = of1[r];
    }
    if (hi == 0) pl[rowbase + lr] = el;
}

// ---------------- Kernel 4: combine + O-proj + residual + FF + rmsnorm, all-MFMA ----------------
__global__ __launch_bounds__(64) void k4_out_ff(
    const unsigned short* __restrict__ xb, const float* __restrict__ po,
    const float* __restrict__ pl,
    const unsigned short* __restrict__ woT, const unsigned short* __restrict__ wiT,
    const unsigned short* __restrict__ wo2T, const float* __restrict__ lnf,
    float* __restrict__ out, int nsplit)
{
    const int l  = threadIdx.x;
    const int lr = l & 31, hi = l >> 5;
    const int row = blockIdx.x * 32 + lr;

    float lsum = 0.f;
    for (int s = 0; s < nsplit; ++s) lsum += pl[(size_t)s*NROWS + row];
    const float linv = 1.0f / lsum;

    float a[3][8];
    #pragma unroll
    for (int t = 0; t < 3; ++t)
        #pragma unroll
        for (int j = 0; j < 8; ++j) a[t][j] = 0.f;
    for (int s = 0; s < nsplit; ++s) {
        const float* pr = po + ((size_t)s*NROWS + row)*D;
        #pragma unroll
        for (int t = 0; t < 3; ++t) {
            if (t == 2 && hi == 1) continue;          // d = 40..47 out of range
            float4 f0 = *(const float4*)(pr + t*16 + hi*8);
            float4 f1 = *(const float4*)(pr + t*16 + hi*8 + 4);
            a[t][0]+=f0.x; a[t][1]+=f0.y; a[t][2]+=f0.z; a[t][3]+=f0.w;
            a[t][4]+=f1.x; a[t][5]+=f1.y; a[t][6]+=f1.z; a[t][7]+=f1.w;
        }
    }
    bf16x8 ab[3];
    #pragma unroll
    for (int t = 0; t < 3; ++t) {
        uint4 u = { cvtpk(a[t][0]*linv, a[t][1]*linv), cvtpk(a[t][2]*linv, a[t][3]*linv),
                    cvtpk(a[t][4]*linv, a[t][5]*linv), cvtpk(a[t][6]*linv, a[t][7]*linv) };
        ab[t] = __builtin_bit_cast(bf16x8, u);
    }

    f32x16 c0 = {0,0,0,0,0,0,0,0,0,0,0,0,0,0,0,0};
    f32x16 c1 = {0,0,0,0,0,0,0,0,0,0,0,0,0,0,0,0};
    #pragma unroll
    for (int t = 0; t < 3; ++t) {
        c0 = __builtin_amdgcn_mfma_f32_32x32x16_bf16(ldfrag(woT + lr*48      + t*16 + hi*8), ab[t], c0, 0,0,0);
        c1 = __builtin_amdgcn_mfma_f32_32x32x16_bf16(ldfrag(woT + (32+lr)*48 + t*16 + hi*8), ab[t], c1, 0,0,0);
    }
    const unsigned short* xr = xb + (size_t)row*XSTR;
    #pragma unroll
    for (int rr = 0; rr < 4; ++rr) {
        ushort4 v = *(const ushort4*)(xr + rr*8 + 4*hi);
        c0[rr*4+0] += bf2f(v.x); c0[rr*4+1] += bf2f(v.y);
        c0[rr*4+2] += bf2f(v.z); c0[rr*4+3] += bf2f(v.w);
    }
    {
        ushort4 v = *(const ushort4*)(xr + 32 + 4*hi);
        c1[0] += bf2f(v.x); c1[1] += bf2f(v.y); c1[2] += bf2f(v.z); c1[3] += bf2f(v.w);
    }

    float ss = 0.f;
    #pragma unroll
    for (int r = 0; r < 16; ++r) ss += c0[r]*c0[r] + c1[r]*c1[r];
    ss += __shfl_xor(ss, 32);
    const float inv2 = rsqrtf(ss * (1.0f/D) + 1e-6f);

    f32x16 t0, t1;
    #pragma unroll
    for (int r = 0; r < 16; ++r) { t0[r] = c0[r]*inv2; t1[r] = c1[r]*inv2; }
    uint4 h0,h1,h2; repack_cl(t0, t1, h0, h1, h2);
    bf16x8 hb[3] = { __builtin_bit_cast(bf16x8, h0),
                     __builtin_bit_cast(bf16x8, h1),
                     __builtin_bit_cast(bf16x8, h2) };

    f32x16 d0 = {0,0,0,0,0,0,0,0,0,0,0,0,0,0,0,0};
    f32x16 d1 = {0,0,0,0,0,0,0,0,0,0,0,0,0,0,0,0};
    #pragma unroll
    for (int t = 0; t < 3; ++t) {
        d0 = __builtin_amdgcn_mfma_f32_32x32x16_bf16(ldfrag(wiT + lr*48      + t*16 + hi*8), hb[t], d0, 0,0,0);
        d1 = __builtin_amdgcn_mfma_f32_32x32x16_bf16(ldfrag(wiT + (32+lr)*48 + t*16 + hi*8), hb[t], d1, 0,0,0);
    }
    #pragma unroll
    for (int r = 0; r < 16; ++r) { d0[r] = fmaxf(d0[r], 0.f); d1[r] = fmaxf(d1[r], 0.f); }
    uint4 g0,g1,g2; repack_cl(d0, d1, g0, g1, g2);
    bf16x8 fb[3] = { __builtin_bit_cast(bf16x8, g0),
                     __builtin_bit_cast(bf16x8, g1),
                     __builtin_bit_cast(bf16x8, g2) };

    f32x16 e0 = {0,0,0,0,0,0,0,0,0,0,0,0,0,0,0,0};
    f32x16 e1 = {0,0,0,0,0,0,0,0,0,0,0,0,0,0,0,0};
    #pragma unroll
    for (int t = 0; t < 3; ++t) {
        e0 = __builtin_amdgcn_mfma_f32_32x32x16_bf16(ldfrag(wo2T + lr*48      + t*16 + hi*8), fb[t], e0, 0,0,0);
        e1 = __builtin_amdgcn_mfma_f32_32x32x16_bf16(ldfrag(wo2T + (32+lr)*48 + t*16 + hi*8), fb[t], e1, 0,0,0);
    }
    #pragma unroll
    for (int r = 0; r < 16; ++r) { e0[r] += c0[r]; e1[r] += c1[r]; }

    float ss2 = 0.f;
    #pragma unroll
    for (int r = 0; r < 16; ++r) ss2 += e0[r]*e0[r] + e1[r]*e1[r];
    ss2 += __shfl_xor(ss2, 32);
    const float inv3 = rsqrtf(ss2 * (1.0f/D) + 1e-6f);

    float* orow = out + (size_t)row * D;
    #pragma unroll
    for (int rr = 0; rr < 4; ++rr) {
        float4 lf = *(const float4*)(lnf + rr*8 + 4*hi);
        float4 v = { e0[rr*4+0]*inv3*lf.x, e0[rr*4+1]*inv3*lf.y,
                     e0[rr*4+2]*inv3*lf.z, e0[rr*4+3]*inv3*lf.w };
        *(float4*)(orow + rr*8 + 4*hi) = v;
    }
    {
        float4 lf = *(const float4*)(lnf + 32 + 4*hi);
        float4 v = { e1[0]*inv3*lf.x, e1[1]*inv3*lf.y, e1[2]*inv3*lf.z, e1[3]*inv3*lf.w };
        *(float4*)(orow + 32 + 4*hi) = v;
    }
}

extern "C" void kernel_launch(void* const* d_in, const int* in_sizes, int n_in,
                              void* d_out, int out_size, void* d_ws, size_t ws_size,
                              hipStream_t stream) {
    const float* embs = (const float*)d_in[0];
    const float* Wa   = (const float*)d_in[1];
    const float* ba   = (const float*)d_in[2];
    const float* ln1  = (const float*)d_in[3];
    const float* Wq   = (const float*)d_in[4];
    const float* Wk   = (const float*)d_in[5];
    const float* Wv   = (const float*)d_in[6];
    const float* Wo   = (const float*)d_in[7];
    const float* ln2  = (const float*)d_in[8];
    const float* wi   = (const float*)d_in[9];
    const float* wo   = (const float*)d_in[10];
    const float* lnf  = (const float*)d_in[11];
    const float* rb   = (const float*)d_in[12];

    char* wsb = (char*)d_ws;
    unsigned short* xb   = (unsigned short*)(wsb);              // NROWS*48*2 = 1,572,864
    unsigned short* qb   = (unsigned short*)(wsb + 1572864);    // 2,097,152
    unsigned short* kbq  = (unsigned short*)(wsb + 3670016);    // 2,097,152
    unsigned short* vT   = (unsigned short*)(wsb + 5767168);    // 2,097,152
    unsigned short* waT  = (unsigned short*)(wsb + 7864320);    // 18,432
    unsigned short* wqT  = (unsigned short*)(wsb + 7882752);    // 6,144
    unsigned short* wkT  = (unsigned short*)(wsb + 7888896);
    unsigned short* wvT  = (unsigned short*)(wsb + 7895040);
    unsigned short* woT  = (unsigned short*)(wsb + 7901184);
    unsigned short* wiT  = (unsigned short*)(wsb + 7907328);
    unsigned short* wo2T = (unsigned short*)(wsb + 7913472);
    // po/pl/btab from 7,919,616

    int nsplit = 8;
    while (nsplit > 1 &&
           (size_t)7919616 + (size_t)nsplit*(2621440 + 65536) + 16384 > ws_size)
        nsplit >>= 1;
    float* po   = (float*)(wsb + 7919616);
    float* pl   = (float*)(wsb + 7919616 + (size_t)nsplit*2621440);
    float* btab = (float*)(wsb + 7919616 + (size_t)nsplit*(2621440 + 65536));
    int klen = S / nsplit;

    k0_prep<<<36, 256, 0, stream>>>(Wa, ba, ln1, Wq, Wk, Wv, Wo, ln2, wi, wo, rb,
                                    waT, wqT, wkT, wvT, woT, wiT, wo2T, btab);
    k1_adapter_qkv<<<NROWS/32, 64, 0, stream>>>(embs, waT, wqT, wkT, wvT, xb, qb, kbq, vT);
    k3_attn_mfma<<<dim3(S/128, B, nsplit), 256, 0, stream>>>(qb, kbq, vT, btab, po, pl, klen);
    k4_out_ff<<<NROWS/32, 64, 0, stream>>>(xb, po, pl, woT, wiT, wo2T, lnf, (float*)d_out, nsplit);
}